// Round 13
// baseline (453.556 us; speedup 1.0000x reference)
//
#include <hip/hip_runtime.h>
#include <hip/hip_fp16.h>
#include <math.h>

// Problem dims
#define LTOT 1024
#define BB   4
#define F_IN 32
#define DM   256
#define DI   512
#define DS   16
#define DTRN 16
#define NXP  48         // DTR + 2*DS
#define NLAY 4
#define NH   4
#define NC   16         // scan chunks
#define CLEN 64         // L / NC
#define ROWS (BB*LTOT)  // 4096

typedef _Float16 half8 __attribute__((ext_vector_type(8)));
typedef float f32x16 __attribute__((ext_vector_type(16)));

__device__ __forceinline__ float siluf_(float x) { return x / (1.0f + expf(-x)); }
__device__ __forceinline__ float softplusf_(float x) {
    if (x > 20.f) return x;
    if (x < -20.f) return expf(x);
    return log1pf(expf(x));
}

// fp16 2-piece split: x ~= hi + lo with ~22-bit combined mantissa
__device__ __forceinline__ void split16(float x, unsigned short& hi, unsigned short& lo) {
    __half h = __float2half(x);
    hi = *(unsigned short*)&h;
    float r = x - __half2float(h);
    __half l = __float2half(r);
    lo = *(unsigned short*)&l;
}

// MFMA fragment-order address for element (r, k) of a matrix with k-dim Kd.
__device__ __forceinline__ size_t fragAddr(int r, int k, int Kd) {
    return ((size_t)((r >> 5) * (Kd >> 4) + (k >> 4)) << 9)
         + (size_t)(((((k >> 3) & 1) << 5) + (r & 31)) * 8 + (k & 7));
}

// ---------------- init: fused weight-split->fragment (blocks 0..1535) + proj (1536..1791) ----
__global__ __launch_bounds__(256) void k_init(const float* __restrict__ x,
                                              const float* __restrict__ pw,
                                              const float* __restrict__ pb,
                                              const float* __restrict__ inw,
                                              const float* __restrict__ outw,
                                              float* __restrict__ h,
                                              unsigned short* __restrict__ hh,
                                              unsigned short* __restrict__ hl,
                                              unsigned short* __restrict__ iwh,
                                              unsigned short* __restrict__ iwl,
                                              unsigned short* __restrict__ owh,
                                              unsigned short* __restrict__ owl) {
    __shared__ float wl[DM][33];
    __shared__ float xl[16][32];
    int bid = blockIdx.x, t = threadIdx.x;
    if (bid < 1536) {   // ---- weight split into fragment order ----
        int q = bid * 256 + t;
        ushort4 h4, l4;
        if (q < 262144) {                          // inw: 4 layers x 1024 rows x K=256
            float4 v = ((const float4*)inw)[q];
            split16(v.x, h4.x, l4.x); split16(v.y, h4.y, l4.y);
            split16(v.z, h4.z, l4.z); split16(v.w, h4.w, l4.w);
            int row = q >> 6, k0 = (q & 63) * 4;
            int lay = row >> 10, rIn = row & 1023;
            size_t fa = (size_t)lay * 262144 + fragAddr(rIn, k0, 256);
            *(ushort4*)(iwh + fa) = h4;
            *(ushort4*)(iwl + fa) = l4;
        } else {
            int rq = q - 262144;                   // outw: 4 layers x 256 rows x K=512
            float4 v = ((const float4*)outw)[rq];
            split16(v.x, h4.x, l4.x); split16(v.y, h4.y, l4.y);
            split16(v.z, h4.z, l4.z); split16(v.w, h4.w, l4.w);
            int row = rq >> 7, k0 = (rq & 127) * 4;
            int lay = row >> 8, rIn = row & 255;
            size_t fa = (size_t)lay * 131072 + fragAddr(rIn, k0, 512);
            *(ushort4*)(owh + fa) = h4;
            *(ushort4*)(owl + fa) = l4;
        }
        return;
    }
    // ---- proj: h = x @ proj_w.T + proj_b (+ fragment-order fp16 emit) ----
    int r0 = (bid - 1536) * 16;
    for (int i = t; i < DM * 32 / 4; i += 256) {
        float4 v = ((const float4*)pw)[i];
        int c = i / 8, k = (i % 8) * 4;
        wl[c][k] = v.x; wl[c][k + 1] = v.y; wl[c][k + 2] = v.z; wl[c][k + 3] = v.w;
    }
    for (int i = t; i < 16 * 32 / 4; i += 256) {
        float4 v = ((const float4*)(x + (size_t)r0 * F_IN))[i];
        int r = i / 8, k = (i % 8) * 4;
        xl[r][k] = v.x; xl[r][k + 1] = v.y; xl[r][k + 2] = v.z; xl[r][k + 3] = v.w;
    }
    __syncthreads();
    int c = t;
    float bias = pb[c];
    float acc[16];
#pragma unroll
    for (int r = 0; r < 16; ++r) acc[r] = bias;
    for (int k = 0; k < 32; ++k) {
        float w = wl[c][k];
#pragma unroll
        for (int r = 0; r < 16; ++r) acc[r] = fmaf(xl[r][k], w, acc[r]);
    }
#pragma unroll
    for (int r = 0; r < 16; ++r) {
        int rr = r0 + r;
        h[(size_t)rr * DM + c] = acc[r];
        unsigned short vh, vl; split16(acc[r], vh, vl);
        size_t fa = fragAddr(rr, c, 256);
        hh[fa] = vh; hl[fa] = vl;
    }
}

// ---------------- gemm_xz (MFMA, fragment-streamed, depth-2 prefetch): xz = h @ inw^T --
__global__ __launch_bounds__(256) void k_gemm_xz(const unsigned short* __restrict__ Ahp,
                                                 const unsigned short* __restrict__ Alp,
                                                 const unsigned short* __restrict__ Bhp,
                                                 const unsigned short* __restrict__ Blp,
                                                 float* __restrict__ C) {
    int t = threadIdx.x;
    int bx = blockIdx.x & 7;
    int by = blockIdx.x >> 3;
    int lane = t & 63, wid = t >> 6;
    int fr = lane & 31, fg = lane >> 5;
    int wr = wid >> 1, wc = wid & 1;
    int rt = by * 2 + wr;
    int ct0 = bx * 4 + wc * 2;
    const half8* pAh = (const half8*)Ahp + (size_t)rt * 1024 + lane;
    const half8* pAl = (const half8*)Alp + (size_t)rt * 1024 + lane;
    const half8* pB0h = (const half8*)Bhp + (size_t)ct0 * 1024 + lane;
    const half8* pB0l = (const half8*)Blp + (size_t)ct0 * 1024 + lane;
    const half8* pB1h = pB0h + 1024;
    const half8* pB1l = pB0l + 1024;
    f32x16 acc[2] = {};
    // depth-2: two named in-flight sets (set0 = even kt, set1 = odd kt)
    half8 ah0 = pAh[0],  al0 = pAl[0];
    half8 b0h0 = pB0h[0], b0l0 = pB0l[0], b1h0 = pB1h[0], b1l0 = pB1l[0];
    half8 ah1 = pAh[64], al1 = pAl[64];
    half8 b0h1 = pB0h[64], b0l1 = pB0l[64], b1h1 = pB1h[64], b1l1 = pB1l[64];
#pragma unroll
    for (int kt = 0; kt < 16; kt += 2) {
        half8 nah, nal, nb0h, nb0l, nb1h, nb1l;
        if (kt + 2 < 16) {
            int o = (kt + 2) * 64;
            nah = pAh[o]; nal = pAl[o];
            nb0h = pB0h[o]; nb0l = pB0l[o];
            nb1h = pB1h[o]; nb1l = pB1l[o];
        }
        acc[0] = __builtin_amdgcn_mfma_f32_32x32x16_f16(ah0, b0h0, acc[0], 0, 0, 0);
        acc[0] = __builtin_amdgcn_mfma_f32_32x32x16_f16(ah0, b0l0, acc[0], 0, 0, 0);
        acc[0] = __builtin_amdgcn_mfma_f32_32x32x16_f16(al0, b0h0, acc[0], 0, 0, 0);
        acc[1] = __builtin_amdgcn_mfma_f32_32x32x16_f16(ah0, b1h0, acc[1], 0, 0, 0);
        acc[1] = __builtin_amdgcn_mfma_f32_32x32x16_f16(ah0, b1l0, acc[1], 0, 0, 0);
        acc[1] = __builtin_amdgcn_mfma_f32_32x32x16_f16(al0, b1h0, acc[1], 0, 0, 0);
        if (kt + 2 < 16) { ah0 = nah; al0 = nal; b0h0 = nb0h; b0l0 = nb0l; b1h0 = nb1h; b1l0 = nb1l; }
        half8 mah, mal, mb0h, mb0l, mb1h, mb1l;
        if (kt + 3 < 16) {
            int o = (kt + 3) * 64;
            mah = pAh[o]; mal = pAl[o];
            mb0h = pB0h[o]; mb0l = pB0l[o];
            mb1h = pB1h[o]; mb1l = pB1l[o];
        }
        acc[0] = __builtin_amdgcn_mfma_f32_32x32x16_f16(ah1, b0h1, acc[0], 0, 0, 0);
        acc[0] = __builtin_amdgcn_mfma_f32_32x32x16_f16(ah1, b0l1, acc[0], 0, 0, 0);
        acc[0] = __builtin_amdgcn_mfma_f32_32x32x16_f16(al1, b0h1, acc[0], 0, 0, 0);
        acc[1] = __builtin_amdgcn_mfma_f32_32x32x16_f16(ah1, b1h1, acc[1], 0, 0, 0);
        acc[1] = __builtin_amdgcn_mfma_f32_32x32x16_f16(ah1, b1l1, acc[1], 0, 0, 0);
        acc[1] = __builtin_amdgcn_mfma_f32_32x32x16_f16(al1, b1h1, acc[1], 0, 0, 0);
        if (kt + 3 < 16) { ah1 = mah; al1 = mal; b0h1 = mb0h; b0l1 = mb0l; b1h1 = mb1h; b1l1 = mb1l; }
    }
    float* Cp = C + (size_t)(by * 64 + wr * 32) * 1024 + bx * 128 + wc * 64;
#pragma unroll
    for (int fc = 0; fc < 2; ++fc) {
#pragma unroll
        for (int reg = 0; reg < 16; ++reg) {
            int row = (reg & 3) + 8 * (reg >> 2) + 4 * fg;
            Cp[(size_t)row * 1024 + fc * 32 + fr] = acc[fc][reg];
        }
    }
}

// ---------------- dbc partial GEMM (split-K by 4) with fused causal conv+silu --------
// 1024 blocks x 16 rows: kp = bid&3, r0 = (bid>>2)*16. Early weight-issue kept.
__global__ __launch_bounds__(256) void k_dbcp(const float* __restrict__ xz,
                                              const float* __restrict__ cw,
                                              const float* __restrict__ cb,
                                              const float* __restrict__ xpw,
                                              float* __restrict__ uc,
                                              float* __restrict__ dbp) {
    __shared__ float us[16][132];
    __shared__ float wsd[48][132];
    int t = threadIdx.x;
    int kp = blockIdx.x & 3;
    int r0 = (blockIdx.x >> 2) * 16;
    int k0 = kp * 128;
    float4* us4 = (float4*)us;
    float4* ws4 = (float4*)wsd;
    // issue weight loads first (registers), write to LDS after conv
    float4 wreg0, wreg1, wreg2, wreg3, wreg4, wreg5;
    {
        int i0 = t;            wreg0 = *(const float4*)(xpw + (size_t)(i0 >> 5) * DI + k0 + (i0 & 31) * 4);
        int i1 = t + 256;      wreg1 = *(const float4*)(xpw + (size_t)(i1 >> 5) * DI + k0 + (i1 & 31) * 4);
        int i2 = t + 512;      wreg2 = *(const float4*)(xpw + (size_t)(i2 >> 5) * DI + k0 + (i2 & 31) * 4);
        int i3 = t + 768;      wreg3 = *(const float4*)(xpw + (size_t)(i3 >> 5) * DI + k0 + (i3 & 31) * 4);
        int i4 = t + 1024;     wreg4 = *(const float4*)(xpw + (size_t)(i4 >> 5) * DI + k0 + (i4 & 31) * 4);
        int i5 = t + 1280;     wreg5 = *(const float4*)(xpw + (size_t)(i5 >> 5) * DI + k0 + (i5 & 31) * 4);
    }
#pragma unroll
    for (int j = 0; j < 2; ++j) {
        int i = t + j * 256;
        int r = i >> 5, kq = i & 31;
        int rr = r0 + r, d = k0 + kq * 4;
        int tt = rr & (LTOT - 1);
        float4 acc = make_float4(cb[d], cb[d + 1], cb[d + 2], cb[d + 3]);
#pragma unroll
        for (int k = 0; k < 4; ++k) {
            int ts = tt - 3 + k;
            if (ts < 0) continue;
            float4 u = *(const float4*)(xz + (size_t)(rr - 3 + k) * 1024 + d);
            acc.x = fmaf(u.x, cw[(d + 0) * 4 + k], acc.x);
            acc.y = fmaf(u.y, cw[(d + 1) * 4 + k], acc.y);
            acc.z = fmaf(u.z, cw[(d + 2) * 4 + k], acc.z);
            acc.w = fmaf(u.w, cw[(d + 3) * 4 + k], acc.w);
        }
        acc.x = siluf_(acc.x); acc.y = siluf_(acc.y); acc.z = siluf_(acc.z); acc.w = siluf_(acc.w);
        us4[r * 33 + kq] = acc;
        *(float4*)(uc + (size_t)rr * DI + d) = acc;
    }
    {
        int i0 = t;        ws4[(i0 >> 5) * 33 + (i0 & 31)] = wreg0;
        int i1 = t + 256;  ws4[(i1 >> 5) * 33 + (i1 & 31)] = wreg1;
        int i2 = t + 512;  ws4[(i2 >> 5) * 33 + (i2 & 31)] = wreg2;
        int i3 = t + 768;  ws4[(i3 >> 5) * 33 + (i3 & 31)] = wreg3;
        int i4 = t + 1024; ws4[(i4 >> 5) * 33 + (i4 & 31)] = wreg4;
        int i5 = t + 1280; ws4[(i5 >> 5) * 33 + (i5 & 31)] = wreg5;
    }
    __syncthreads();
    int tx = t & 15, ty = t >> 4;   // ty = row (16), tx*3 = col triple
    const float4* ua = us4 + ty * 33;
    const float4* w0p = ws4 + (tx * 3) * 33;
    const float4* w1p = w0p + 33;
    const float4* w2p = w0p + 66;
    float a0 = 0.f, a1 = 0.f, a2 = 0.f;
#pragma unroll 4
    for (int kq = 0; kq < 32; ++kq) {
        float4 u0 = ua[kq];
        float4 w0 = w0p[kq], w1 = w1p[kq], w2 = w2p[kq];
        a0 = fmaf(u0.x, w0.x, a0); a0 = fmaf(u0.y, w0.y, a0);
        a0 = fmaf(u0.z, w0.z, a0); a0 = fmaf(u0.w, w0.w, a0);
        a1 = fmaf(u0.x, w1.x, a1); a1 = fmaf(u0.y, w1.y, a1);
        a1 = fmaf(u0.z, w1.z, a1); a1 = fmaf(u0.w, w1.w, a1);
        a2 = fmaf(u0.x, w2.x, a2); a2 = fmaf(u0.y, w2.y, a2);
        a2 = fmaf(u0.z, w2.z, a2); a2 = fmaf(u0.w, w2.w, a2);
    }
    float* outp = dbp + (size_t)(r0 + ty) * 192 + kp * 48 + tx * 3;
    outp[0] = a0; outp[1] = a1; outp[2] = a2;
}

// ---------------- dbc reduce + BC extract + delta (512 blocks x 8 rows) ----------------
__global__ __launch_bounds__(256) void k_dbcr(const float* __restrict__ dbp,
                                              const float* __restrict__ dtw,
                                              const float* __restrict__ dtb,
                                              float* __restrict__ delta,
                                              float* __restrict__ BC) {
    __shared__ float dbl[8][NXP];
    int t = threadIdx.x;
    int r0 = blockIdx.x * 8;
    if (t < 128) {
        int r = t >> 4, c3 = (t & 15) * 3;
        const float* pp = dbp + (size_t)(r0 + r) * 192 + c3;
#pragma unroll
        for (int j = 0; j < 3; ++j) {
            float s = pp[j] + pp[48 + j] + pp[96 + j] + pp[144 + j];
            dbl[r][c3 + j] = s;
            int cj = c3 + j;
            if (cj >= 16) BC[(size_t)(r0 + r) * 32 + (cj - 16)] = s;
        }
    }
    __syncthreads();
    {
        int c0 = t * 2;
        float wd0[16], wd1[16];
        const float4* q0 = (const float4*)(dtw + (size_t)c0 * 16);
        const float4* q1 = (const float4*)(dtw + (size_t)(c0 + 1) * 16);
#pragma unroll
        for (int j = 0; j < 4; ++j) { *(float4*)&wd0[j * 4] = q0[j]; *(float4*)&wd1[j * 4] = q1[j]; }
        float bb0 = dtb[c0], bb1 = dtb[c0 + 1];
        for (int r = 0; r < 8; ++r) {
            float s0 = bb0, s1 = bb1;
#pragma unroll
            for (int k = 0; k < 16; ++k) {
                float dv = dbl[r][k];
                s0 = fmaf(dv, wd0[k], s0);
                s1 = fmaf(dv, wd1[k], s1);
            }
            *(float2*)(delta + (size_t)(r0 + r) * DI + c0) =
                make_float2(softplusf_(s0), softplusf_(s1));
        }
    }
}

// ---------------- scan pass A ----------------
__global__ __launch_bounds__(256) void k_scanA(const float* __restrict__ delta,
                                               const float* __restrict__ uc,
                                               const float* __restrict__ BC,
                                               const float* __restrict__ A_log,
                                               float* __restrict__ P,
                                               float* __restrict__ hL) {
    __shared__ float2 du2[CLEN][16];
    __shared__ float  Bl[CLEN][16];
    int bid = blockIdx.x;
    int c = bid & 15, dblk = (bid >> 4) & 31, b = bid >> 9;
    int d0 = dblk * 16, t0 = c * CLEN;
    int t = threadIdx.x;
    {
        int row = t >> 2, hf = (t & 3) * 4;
        size_t rbase = (size_t)(b * LTOT + t0 + row);
        float4 dv = *(const float4*)(delta + rbase * DI + d0 + hf);
        float4 uv = *(const float4*)(uc + rbase * DI + d0 + hf);
        float4* dst = (float4*)&du2[row][hf];
        dst[0] = make_float4(dv.x, uv.x, dv.y, uv.y);
        dst[1] = make_float4(dv.z, uv.z, dv.w, uv.w);
        *(float4*)&Bl[row][hf] = *(const float4*)(BC + rbase * 32 + hf);
    }
    __syncthreads();
    int n = t & 15, dn = t >> 4;
    float Ac = -expf(A_log[(size_t)(d0 + dn) * DS + n]);
    float h = 0.f, Pp = 1.f;
#pragma unroll 8
    for (int k = 0; k < CLEN; ++k) {
        float2 du = du2[k][dn];
        float Bv = Bl[k][n];
        float a = expf(du.x * Ac);
        Pp *= a;
        h = fmaf(a, h, du.x * du.y * Bv);
    }
    size_t idx = ((size_t)(b * NC + c)) * (DI * DS) + (size_t)d0 * DS + t;
    P[idx] = Pp;
    hL[idx] = h;
}

// ---------------- scan pass C (ytmp LDS reduce; Hin loads prefetched after barrier) ---
__global__ __launch_bounds__(256) void k_scanC(const float* __restrict__ delta,
                                               const float* __restrict__ uc,
                                               const float* __restrict__ BC,
                                               const float* __restrict__ A_log,
                                               const float* __restrict__ P,
                                               const float* __restrict__ hL,
                                               const float* __restrict__ Dp,
                                               const float* __restrict__ xz,
                                               unsigned short* __restrict__ yh,
                                               unsigned short* __restrict__ yl) {
    __shared__ float2 du2[CLEN][16];
    __shared__ float2 bc2[CLEN][16];
    __shared__ float  zs[CLEN][16];
    __shared__ float  ytmp[16][16][20];
    int bid = blockIdx.x;
    int c = bid & 15, dblk = (bid >> 4) & 31, b = bid >> 9;
    int d0 = dblk * 16, t0 = c * CLEN;
    int t = threadIdx.x;
    {
        int row = t >> 2, hf = (t & 3) * 4;
        size_t rbase = (size_t)(b * LTOT + t0 + row);
        float4 dv = *(const float4*)(delta + rbase * DI + d0 + hf);
        float4 uv = *(const float4*)(uc + rbase * DI + d0 + hf);
        float4* dst = (float4*)&du2[row][hf];
        dst[0] = make_float4(dv.x, uv.x, dv.y, uv.y);
        dst[1] = make_float4(dv.z, uv.z, dv.w, uv.w);
        float4 bv = *(const float4*)(BC + rbase * 32 + hf);
        float4 cv = *(const float4*)(BC + rbase * 32 + 16 + hf);
        float4* bdst = (float4*)&bc2[row][hf];
        bdst[0] = make_float4(bv.x, cv.x, bv.y, cv.y);
        bdst[1] = make_float4(bv.z, cv.z, bv.w, cv.w);
        *(float4*)&zs[row][hf] = *(const float4*)(xz + rbase * 1024 + 512 + d0 + hf);
    }
    __syncthreads();
    int n = t & 15, dn = t >> 4;
    float Ac = -expf(A_log[(size_t)(d0 + dn) * DS + n]);
    // Hin: fully-unrolled guarded prefetch (independent loads), then exact-order chain
    float Hin = 0.f;
    {
        float pv[15], hv[15];
#pragma unroll
        for (int cc = 0; cc < 15; ++cc) {
            pv[cc] = 0.f; hv[cc] = 0.f;
            if (cc < c) {
                size_t idx = ((size_t)(b * NC + cc)) * (DI * DS) + (size_t)d0 * DS + t;
                pv[cc] = P[idx];
                hv[cc] = hL[idx];
            }
        }
#pragma unroll
        for (int cc = 0; cc < 15; ++cc) {
            if (cc < c) Hin = fmaf(pv[cc], Hin, hv[cc]);
        }
    }
    float h = Hin;
    int rdn = t & 15, rk = t >> 4;
    float DpV = Dp[d0 + rdn];
    for (int s = 0; s < CLEN / 16; ++s) {
#pragma unroll
        for (int kk = 0; kk < 16; ++kk) {
            int k = s * 16 + kk;
            float2 du = du2[k][dn];
            float2 bc = bc2[k][n];
            float a = expf(du.x * Ac);
            h = fmaf(a, h, du.x * du.y * bc.x);
            ytmp[kk][dn][n] = h * bc.y;
        }
        __syncthreads();
        {
            const float* rowp = &ytmp[rk][rdn][0];
            float4 v0 = *(const float4*)(rowp + 0);
            float4 v1 = *(const float4*)(rowp + 4);
            float4 v2 = *(const float4*)(rowp + 8);
            float4 v3 = *(const float4*)(rowp + 12);
            float y = ((v0.x + v0.y) + (v0.z + v0.w)) + ((v1.x + v1.y) + (v1.z + v1.w))
                    + ((v2.x + v2.y) + (v2.z + v2.w)) + ((v3.x + v3.y) + (v3.z + v3.w));
            float uu = du2[s * 16 + rk][rdn].y;
            float z = zs[s * 16 + rk][rdn];
            size_t rb2 = (size_t)(b * LTOT + t0 + s * 16 + rk);
            float val = fmaf(uu, DpV, y) * siluf_(z);
            unsigned short vh, vl; split16(val, vh, vl);
            size_t fa = fragAddr((int)rb2, d0 + rdn, 512);
            yh[fa] = vh; yl[fa] = vl;
        }
        __syncthreads();
    }
}

// ---------------- gemm_out (MFMA, fragment-streamed, depth-2, split-K4) ----------------
__global__ __launch_bounds__(256) void k_gemm_out(const unsigned short* __restrict__ Ahp,
                                                  const unsigned short* __restrict__ Alp,
                                                  const unsigned short* __restrict__ Bhp,
                                                  const unsigned short* __restrict__ Blp,
                                                  float* __restrict__ p01,
                                                  float* __restrict__ p23) {
    int t = threadIdx.x;
    int bx = blockIdx.x & 1;
    int by = (blockIdx.x >> 1) & 63;
    int kp = blockIdx.x >> 7;
    int lane = t & 63, wid = t >> 6;
    int fr = lane & 31, fg = lane >> 5;
    int wr = wid >> 1, wc = wid & 1;
    int rt = by * 2 + wr;
    int ct0 = bx * 4 + wc * 2;
    const half8* pAh = (const half8*)Ahp + (size_t)rt * 2048 + (size_t)kp * 512 + lane;
    const half8* pAl = (const half8*)Alp + (size_t)rt * 2048 + (size_t)kp * 512 + lane;
    const half8* pB0h = (const half8*)Bhp + (size_t)ct0 * 2048 + (size_t)kp * 512 + lane;
    const half8* pB0l = (const half8*)Blp + (size_t)ct0 * 2048 + (size_t)kp * 512 + lane;
    const half8* pB1h = pB0h + 2048;
    const half8* pB1l = pB0l + 2048;
    f32x16 acc[2] = {};
    half8 ah0 = pAh[0],  al0 = pAl[0];
    half8 b0h0 = pB0h[0], b0l0 = pB0l[0], b1h0 = pB1h[0], b1l0 = pB1l[0];
    half8 ah1 = pAh[64], al1 = pAl[64];
    half8 b0h1 = pB0h[64], b0l1 = pB0l[64], b1h1 = pB1h[64], b1l1 = pB1l[64];
#pragma unroll
    for (int kt = 0; kt < 8; kt += 2) {
        half8 nah, nal, nb0h, nb0l, nb1h, nb1l;
        if (kt + 2 < 8) {
            int o = (kt + 2) * 64;
            nah = pAh[o]; nal = pAl[o];
            nb0h = pB0h[o]; nb0l = pB0l[o];
            nb1h = pB1h[o]; nb1l = pB1l[o];
        }
        acc[0] = __builtin_amdgcn_mfma_f32_32x32x16_f16(ah0, b0h0, acc[0], 0, 0, 0);
        acc[0] = __builtin_amdgcn_mfma_f32_32x32x16_f16(ah0, b0l0, acc[0], 0, 0, 0);
        acc[0] = __builtin_amdgcn_mfma_f32_32x32x16_f16(al0, b0h0, acc[0], 0, 0, 0);
        acc[1] = __builtin_amdgcn_mfma_f32_32x32x16_f16(ah0, b1h0, acc[1], 0, 0, 0);
        acc[1] = __builtin_amdgcn_mfma_f32_32x32x16_f16(ah0, b1l0, acc[1], 0, 0, 0);
        acc[1] = __builtin_amdgcn_mfma_f32_32x32x16_f16(al0, b1h0, acc[1], 0, 0, 0);
        if (kt + 2 < 8) { ah0 = nah; al0 = nal; b0h0 = nb0h; b0l0 = nb0l; b1h0 = nb1h; b1l0 = nb1l; }
        half8 mah, mal, mb0h, mb0l, mb1h, mb1l;
        if (kt + 3 < 8) {
            int o = (kt + 3) * 64;
            mah = pAh[o]; mal = pAl[o];
            mb0h = pB0h[o]; mb0l = pB0l[o];
            mb1h = pB1h[o]; mb1l = pB1l[o];
        }
        acc[0] = __builtin_amdgcn_mfma_f32_32x32x16_f16(ah1, b0h1, acc[0], 0, 0, 0);
        acc[0] = __builtin_amdgcn_mfma_f32_32x32x16_f16(ah1, b0l1, acc[0], 0, 0, 0);
        acc[0] = __builtin_amdgcn_mfma_f32_32x32x16_f16(al1, b0h1, acc[0], 0, 0, 0);
        acc[1] = __builtin_amdgcn_mfma_f32_32x32x16_f16(ah1, b1h1, acc[1], 0, 0, 0);
        acc[1] = __builtin_amdgcn_mfma_f32_32x32x16_f16(ah1, b1l1, acc[1], 0, 0, 0);
        acc[1] = __builtin_amdgcn_mfma_f32_32x32x16_f16(al1, b1h1, acc[1], 0, 0, 0);
        if (kt + 3 < 8) { ah1 = mah; al1 = mal; b0h1 = mb0h; b0l1 = mb0l; b1h1 = mb1h; b1l1 = mb1l; }
    }
    float* pbase = (kp < 2 ? p01 : p23) + (size_t)(kp & 1) * (ROWS * DM);
    float* Cp = pbase + (size_t)(by * 64 + wr * 32) * DM + bx * 128 + wc * 64;
#pragma unroll
    for (int fc = 0; fc < 2; ++fc) {
#pragma unroll
        for (int reg = 0; reg < 16; ++reg) {
            int row = (reg & 3) + 8 * (reg >> 2) + 4 * fg;
            Cp[(size_t)row * DM + fc * 32 + fr] = acc[fc][reg];
        }
    }
}

// ---------------- layernorm + residual (sums 4 gemm_out partials, emits h16) --------
__global__ __launch_bounds__(256) void k_ln_res(const float* __restrict__ p01,
                                                const float* __restrict__ p23,
                                                const float* __restrict__ g,
                                                const float* __restrict__ bb,
                                                float* __restrict__ h,
                                                unsigned short* __restrict__ hh,
                                                unsigned short* __restrict__ hl) {
    __shared__ float scratch[4];
    int r = blockIdx.x, t = threadIdx.x;
    size_t idx = (size_t)r * DM + t;
    float v = p01[idx] + p01[idx + (size_t)ROWS * DM] + p23[idx] + p23[idx + (size_t)ROWS * DM];
    float s = v;
#pragma unroll
    for (int m = 32; m >= 1; m >>= 1) s += __shfl_xor(s, m, 64);
    if ((t & 63) == 0) scratch[t >> 6] = s;
    __syncthreads();
    float mu = (scratch[0] + scratch[1] + scratch[2] + scratch[3]) * (1.f / DM);
    __syncthreads();
    float d = v - mu;
    float s2 = d * d;
#pragma unroll
    for (int m = 32; m >= 1; m >>= 1) s2 += __shfl_xor(s2, m, 64);
    if ((t & 63) == 0) scratch[t >> 6] = s2;
    __syncthreads();
    float var = (scratch[0] + scratch[1] + scratch[2] + scratch[3]) * (1.f / DM);
    float rstd = 1.f / sqrtf(var + 1e-5f);
    float nv = h[idx] + d * rstd * g[t] + bb[t];
    h[idx] = nv;
    unsigned short vh, vl; split16(nv, vh, vl);
    size_t fa = fragAddr(r, t, 256);
    hh[fa] = vh; hl[fa] = vl;
}

// ---------------- mean over L (partials, deterministic) ----------------
__global__ __launch_bounds__(256) void k_meanp(const float* __restrict__ h,
                                               float* __restrict__ part) {
    int bid = blockIdx.x;
    int b = bid >> 3, g = bid & 7;
    int t = threadIdx.x;
    float s = 0.f;
    for (int k = 0; k < 128; ++k)
        s += h[(size_t)(b * LTOT + g * 128 + k) * DM + t];
    part[(size_t)bid * DM + t] = s;
}

// ---------------- head (float4 weight streams, same FMA order) ----------------
__global__ __launch_bounds__(256) void k_head(const float* __restrict__ part,
                                              const float* __restrict__ w1,
                                              const float* __restrict__ b1,
                                              const float* __restrict__ w2,
                                              const float* __restrict__ b2,
                                              float* __restrict__ out) {
    __shared__ float pl[DM], hl[DM];
    int b = blockIdx.x, t = threadIdx.x;
    float s = 0.f;
    for (int g = 0; g < 8; ++g) s += part[(size_t)(b * 8 + g) * DM + t];
    pl[t] = s * (1.f / LTOT);
    __syncthreads();
    float a = b1[t];
    const float4* w1p = (const float4*)(w1 + (size_t)t * DM);
    for (int k = 0; k < DM / 4; ++k) {
        float4 w = w1p[k];
        a = fmaf(pl[k * 4 + 0], w.x, a);
        a = fmaf(pl[k * 4 + 1], w.y, a);
        a = fmaf(pl[k * 4 + 2], w.z, a);
        a = fmaf(pl[k * 4 + 3], w.w, a);
    }
    hl[t] = fmaxf(a, 0.f);
    __syncthreads();
    if (t < NH) {
        float o = b2[t];
        const float4* w2p = (const float4*)(w2 + (size_t)t * DM);
        for (int k = 0; k < DM / 4; ++k) {
            float4 w = w2p[k];
            o = fmaf(hl[k * 4 + 0], w.x, o);
            o = fmaf(hl[k * 4 + 1], w.y, o);
            o = fmaf(hl[k * 4 + 2], w.z, o);
            o = fmaf(hl[k * 4 + 3], w.w, o);
        }
        out[b * NH + t] = o;
    }
}

extern "C" void kernel_launch(void* const* d_in, const int* in_sizes, int n_in,
                              void* d_out, int out_size, void* d_ws, size_t ws_size,
                              hipStream_t stream) {
    const float* x        = (const float*)d_in[0];
    const float* proj_w   = (const float*)d_in[1];
    const float* proj_b   = (const float*)d_in[2];
    const float* inproj_w = (const float*)d_in[3];
    const float* conv_w   = (const float*)d_in[4];
    const float* conv_b   = (const float*)d_in[5];
    const float* xproj_w  = (const float*)d_in[6];
    const float* dtproj_w = (const float*)d_in[7];
    const float* dtproj_b = (const float*)d_in[8];
    const float* A_log    = (const float*)d_in[9];
    const float* Dp       = (const float*)d_in[10];
    const float* outproj_w= (const float*)d_in[11];
    const float* ln_g     = (const float*)d_in[12];
    const float* ln_b     = (const float*)d_in[13];
    const float* head_w1  = (const float*)d_in[14];
    const float* head_b1  = (const float*)d_in[15];
    const float* head_w2  = (const float*)d_in[16];
    const float* head_b2  = (const float*)d_in[17];

    float* ws    = (float*)d_ws;
    float* h     = ws;                    // 1,048,576 f
    float* xz    = h + 1048576;           // 4,194,304 f
    float* uc    = xz + 4194304;          // 2,097,152 f
    float* dbp   = uc + 2097152;          //   786,432 f (4096*192 dbc partials)
    float* delta = dbp + 786432;          // 2,097,152 f
    float* BC    = delta + 2097152;       //   131,072 f
    float* Pbuf  = BC + 131072;           //   524,288 f
    float* hLbuf = Pbuf + 524288;         //   524,288 f
    float* p01   = hLbuf + 524288;        // 2,097,152 f (gemm_out partials 0,1)
    float* p23   = p01 + 2097152;         // 2,097,152 f (gemm_out partials 2,3)
    float* part  = p23 + 2097152;         //     8,192 f
    unsigned short* h_hi  = (unsigned short*)(part + 8192);  // 4096*256 ush (fragment order)
    unsigned short* h_lo  = h_hi + 1048576;
    unsigned short* y_hi  = h_lo + 1048576;                  // 4096*512 ush (fragment order)
    unsigned short* y_lo  = y_hi + 2097152;
    unsigned short* iw_hi = y_lo + 2097152;                  // 4*1024*256 ush (fragment order)
    unsigned short* iw_lo = iw_hi + 1048576;
    unsigned short* ow_hi = iw_lo + 1048576;                 // 4*256*512 ush (fragment order)
    unsigned short* ow_lo = ow_hi + 524288;

    k_init<<<1792, 256, 0, stream>>>(x, proj_w, proj_b, inproj_w, outproj_w,
                                     h, h_hi, h_lo, iw_hi, iw_lo, ow_hi, ow_lo);

    for (int i = 0; i < NLAY; ++i) {
        const float* cwi  = conv_w + (size_t)i * DI * 4;
        const float* cbi  = conv_b + (size_t)i * DI;
        const float* xpw  = xproj_w + (size_t)i * NXP * DI;
        const float* dtw  = dtproj_w + (size_t)i * DI * DTRN;
        const float* dtb  = dtproj_b + (size_t)i * DI;
        const float* Ali  = A_log + (size_t)i * DI * DS;
        const float* Dpi  = Dp + (size_t)i * DI;
        const float* gi   = ln_g + (size_t)i * DM;
        const float* bi   = ln_b + (size_t)i * DM;

        k_gemm_xz<<<512, 256, 0, stream>>>(h_hi, h_lo,
                                           iw_hi + (size_t)i * 262144, iw_lo + (size_t)i * 262144, xz);
        k_dbcp<<<1024, 256, 0, stream>>>(xz, cwi, cbi, xpw, uc, dbp);
        k_dbcr<<<ROWS / 8, 256, 0, stream>>>(dbp, dtw, dtb, delta, BC);
        k_scanA<<<BB * 32 * NC, 256, 0, stream>>>(delta, uc, BC, Ali, Pbuf, hLbuf);
        k_scanC<<<BB * 32 * NC, 256, 0, stream>>>(delta, uc, BC, Ali, Pbuf, hLbuf, Dpi, xz, y_hi, y_lo);
        k_gemm_out<<<512, 256, 0, stream>>>(y_hi, y_lo,
                                            ow_hi + (size_t)i * 131072, ow_lo + (size_t)i * 131072,
                                            p01, p23);
        k_ln_res<<<ROWS, 256, 0, stream>>>(p01, p23, gi, bi, h, h_hi, h_lo);
    }

    k_meanp<<<32, 256, 0, stream>>>(h, part);
    k_head<<<BB, 256, 0, stream>>>(part, head_w1, head_b1, head_w2, head_b2, (float*)d_out);
}

// Round 14
// 449.903 us; speedup vs baseline: 1.0081x; 1.0081x over previous
//
#include <hip/hip_runtime.h>
#include <hip/hip_fp16.h>
#include <math.h>

// Problem dims
#define LTOT 1024
#define BB   4
#define F_IN 32
#define DM   256
#define DI   512
#define DS   16
#define DTRN 16
#define NXP  48         // DTR + 2*DS
#define NLAY 4
#define NH   4
#define NC   16         // scan chunks
#define CLEN 64         // L / NC
#define ROWS (BB*LTOT)  // 4096

typedef _Float16 half8 __attribute__((ext_vector_type(8)));
typedef float f32x16 __attribute__((ext_vector_type(16)));

__device__ __forceinline__ float siluf_(float x) { return x / (1.0f + expf(-x)); }
__device__ __forceinline__ float softplusf_(float x) {
    if (x > 20.f) return x;
    if (x < -20.f) return expf(x);
    return log1pf(expf(x));
}

// fp16 2-piece split: x ~= hi + lo with ~22-bit combined mantissa
__device__ __forceinline__ void split16(float x, unsigned short& hi, unsigned short& lo) {
    __half h = __float2half(x);
    hi = *(unsigned short*)&h;
    float r = x - __half2float(h);
    __half l = __float2half(r);
    lo = *(unsigned short*)&l;
}

// MFMA fragment-order address for element (r, k) of a matrix with k-dim Kd.
__device__ __forceinline__ size_t fragAddr(int r, int k, int Kd) {
    return ((size_t)((r >> 5) * (Kd >> 4) + (k >> 4)) << 9)
         + (size_t)(((((k >> 3) & 1) << 5) + (r & 31)) * 8 + (k & 7));
}

// ---------------- init: fused weight-split->fragment (blocks 0..1535) + proj (1536..1791) ----
__global__ __launch_bounds__(256) void k_init(const float* __restrict__ x,
                                              const float* __restrict__ pw,
                                              const float* __restrict__ pb,
                                              const float* __restrict__ inw,
                                              const float* __restrict__ outw,
                                              float* __restrict__ h,
                                              unsigned short* __restrict__ hh,
                                              unsigned short* __restrict__ hl,
                                              unsigned short* __restrict__ iwh,
                                              unsigned short* __restrict__ iwl,
                                              unsigned short* __restrict__ owh,
                                              unsigned short* __restrict__ owl) {
    __shared__ float wl[DM][33];
    __shared__ float xl[16][32];
    int bid = blockIdx.x, t = threadIdx.x;
    if (bid < 1536) {   // ---- weight split into fragment order ----
        int q = bid * 256 + t;
        ushort4 h4, l4;
        if (q < 262144) {                          // inw: 4 layers x 1024 rows x K=256
            float4 v = ((const float4*)inw)[q];
            split16(v.x, h4.x, l4.x); split16(v.y, h4.y, l4.y);
            split16(v.z, h4.z, l4.z); split16(v.w, h4.w, l4.w);
            int row = q >> 6, k0 = (q & 63) * 4;
            int lay = row >> 10, rIn = row & 1023;
            size_t fa = (size_t)lay * 262144 + fragAddr(rIn, k0, 256);
            *(ushort4*)(iwh + fa) = h4;
            *(ushort4*)(iwl + fa) = l4;
        } else {
            int rq = q - 262144;                   // outw: 4 layers x 256 rows x K=512
            float4 v = ((const float4*)outw)[rq];
            split16(v.x, h4.x, l4.x); split16(v.y, h4.y, l4.y);
            split16(v.z, h4.z, l4.z); split16(v.w, h4.w, l4.w);
            int row = rq >> 7, k0 = (rq & 127) * 4;
            int lay = row >> 8, rIn = row & 255;
            size_t fa = (size_t)lay * 131072 + fragAddr(rIn, k0, 512);
            *(ushort4*)(owh + fa) = h4;
            *(ushort4*)(owl + fa) = l4;
        }
        return;
    }
    // ---- proj: h = x @ proj_w.T + proj_b (+ fragment-order fp16 emit) ----
    int r0 = (bid - 1536) * 16;
    for (int i = t; i < DM * 32 / 4; i += 256) {
        float4 v = ((const float4*)pw)[i];
        int c = i / 8, k = (i % 8) * 4;
        wl[c][k] = v.x; wl[c][k + 1] = v.y; wl[c][k + 2] = v.z; wl[c][k + 3] = v.w;
    }
    for (int i = t; i < 16 * 32 / 4; i += 256) {
        float4 v = ((const float4*)(x + (size_t)r0 * F_IN))[i];
        int r = i / 8, k = (i % 8) * 4;
        xl[r][k] = v.x; xl[r][k + 1] = v.y; xl[r][k + 2] = v.z; xl[r][k + 3] = v.w;
    }
    __syncthreads();
    int c = t;
    float bias = pb[c];
    float acc[16];
#pragma unroll
    for (int r = 0; r < 16; ++r) acc[r] = bias;
    for (int k = 0; k < 32; ++k) {
        float w = wl[c][k];
#pragma unroll
        for (int r = 0; r < 16; ++r) acc[r] = fmaf(xl[r][k], w, acc[r]);
    }
#pragma unroll
    for (int r = 0; r < 16; ++r) {
        int rr = r0 + r;
        h[(size_t)rr * DM + c] = acc[r];
        unsigned short vh, vl; split16(acc[r], vh, vl);
        size_t fa = fragAddr(rr, c, 256);
        hh[fa] = vh; hl[fa] = vl;
    }
}

// ---------------- gemm_xz (MFMA, fragment-streamed, depth-2, 1024 blocks x 64x64) -----
__global__ __launch_bounds__(256) void k_gemm_xz(const unsigned short* __restrict__ Ahp,
                                                 const unsigned short* __restrict__ Alp,
                                                 const unsigned short* __restrict__ Bhp,
                                                 const unsigned short* __restrict__ Blp,
                                                 float* __restrict__ C) {
    int t = threadIdx.x;
    int bx = blockIdx.x & 15;     // colblock of 64
    int by = blockIdx.x >> 4;     // rowblock of 64
    int lane = t & 63, wid = t >> 6;
    int fr = lane & 31, fg = lane >> 5;
    int wr = wid >> 1, wc = wid & 1;
    int rt = by * 2 + wr;
    int ct = bx * 2 + wc;
    const half8* pAh = (const half8*)Ahp + (size_t)rt * 1024 + lane;
    const half8* pAl = (const half8*)Alp + (size_t)rt * 1024 + lane;
    const half8* pBh = (const half8*)Bhp + (size_t)ct * 1024 + lane;
    const half8* pBl = (const half8*)Blp + (size_t)ct * 1024 + lane;
    f32x16 acc = {};
    half8 ah0 = pAh[0],  al0 = pAl[0],  bh0 = pBh[0],  bl0 = pBl[0];
    half8 ah1 = pAh[64], al1 = pAl[64], bh1 = pBh[64], bl1 = pBl[64];
#pragma unroll
    for (int kt = 0; kt < 16; kt += 2) {
        half8 nah, nal, nbh, nbl;
        if (kt + 2 < 16) {
            int o = (kt + 2) * 64;
            nah = pAh[o]; nal = pAl[o]; nbh = pBh[o]; nbl = pBl[o];
        }
        acc = __builtin_amdgcn_mfma_f32_32x32x16_f16(ah0, bh0, acc, 0, 0, 0);
        acc = __builtin_amdgcn_mfma_f32_32x32x16_f16(ah0, bl0, acc, 0, 0, 0);
        acc = __builtin_amdgcn_mfma_f32_32x32x16_f16(al0, bh0, acc, 0, 0, 0);
        if (kt + 2 < 16) { ah0 = nah; al0 = nal; bh0 = nbh; bl0 = nbl; }
        half8 mah, mal, mbh, mbl;
        if (kt + 3 < 16) {
            int o = (kt + 3) * 64;
            mah = pAh[o]; mal = pAl[o]; mbh = pBh[o]; mbl = pBl[o];
        }
        acc = __builtin_amdgcn_mfma_f32_32x32x16_f16(ah1, bh1, acc, 0, 0, 0);
        acc = __builtin_amdgcn_mfma_f32_32x32x16_f16(ah1, bl1, acc, 0, 0, 0);
        acc = __builtin_amdgcn_mfma_f32_32x32x16_f16(al1, bh1, acc, 0, 0, 0);
        if (kt + 3 < 16) { ah1 = mah; al1 = mal; bh1 = mbh; bl1 = mbl; }
    }
    float* Cp = C + (size_t)(by * 64 + wr * 32) * 1024 + bx * 64 + wc * 32;
#pragma unroll
    for (int reg = 0; reg < 16; ++reg) {
        int row = (reg & 3) + 8 * (reg >> 2) + 4 * fg;
        Cp[(size_t)row * 1024 + fr] = acc[reg];
    }
}

// ---------------- dbc partial GEMM (split-K by 4) with fused causal conv+silu --------
// R12-proven form: 512 blocks x 32 rows, early weight-issue.
__global__ __launch_bounds__(256) void k_dbcp(const float* __restrict__ xz,
                                              const float* __restrict__ cw,
                                              const float* __restrict__ cb,
                                              const float* __restrict__ xpw,
                                              float* __restrict__ uc,
                                              float* __restrict__ dbp) {
    __shared__ float us[32][132];
    __shared__ float wsd[48][132];
    int t = threadIdx.x;
    int kp = blockIdx.x & 3;
    int r0 = (blockIdx.x >> 2) * 32;
    int k0 = kp * 128;
    float4* us4 = (float4*)us;
    float4* ws4 = (float4*)wsd;
    float4 wreg0, wreg1, wreg2, wreg3, wreg4, wreg5;
    {
        int i0 = t;            wreg0 = *(const float4*)(xpw + (size_t)(i0 >> 5) * DI + k0 + (i0 & 31) * 4);
        int i1 = t + 256;      wreg1 = *(const float4*)(xpw + (size_t)(i1 >> 5) * DI + k0 + (i1 & 31) * 4);
        int i2 = t + 512;      wreg2 = *(const float4*)(xpw + (size_t)(i2 >> 5) * DI + k0 + (i2 & 31) * 4);
        int i3 = t + 768;      wreg3 = *(const float4*)(xpw + (size_t)(i3 >> 5) * DI + k0 + (i3 & 31) * 4);
        int i4 = t + 1024;     wreg4 = *(const float4*)(xpw + (size_t)(i4 >> 5) * DI + k0 + (i4 & 31) * 4);
        int i5 = t + 1280;     wreg5 = *(const float4*)(xpw + (size_t)(i5 >> 5) * DI + k0 + (i5 & 31) * 4);
    }
#pragma unroll
    for (int j = 0; j < 4; ++j) {
        int i = t + j * 256;
        int r = i >> 5, kq = i & 31;
        int rr = r0 + r, d = k0 + kq * 4;
        int tt = rr & (LTOT - 1);
        float4 acc = make_float4(cb[d], cb[d + 1], cb[d + 2], cb[d + 3]);
#pragma unroll
        for (int k = 0; k < 4; ++k) {
            int ts = tt - 3 + k;
            if (ts < 0) continue;
            float4 u = *(const float4*)(xz + (size_t)(rr - 3 + k) * 1024 + d);
            acc.x = fmaf(u.x, cw[(d + 0) * 4 + k], acc.x);
            acc.y = fmaf(u.y, cw[(d + 1) * 4 + k], acc.y);
            acc.z = fmaf(u.z, cw[(d + 2) * 4 + k], acc.z);
            acc.w = fmaf(u.w, cw[(d + 3) * 4 + k], acc.w);
        }
        acc.x = siluf_(acc.x); acc.y = siluf_(acc.y); acc.z = siluf_(acc.z); acc.w = siluf_(acc.w);
        us4[r * 33 + kq] = acc;
        *(float4*)(uc + (size_t)rr * DI + d) = acc;
    }
    {
        int i0 = t;        ws4[(i0 >> 5) * 33 + (i0 & 31)] = wreg0;
        int i1 = t + 256;  ws4[(i1 >> 5) * 33 + (i1 & 31)] = wreg1;
        int i2 = t + 512;  ws4[(i2 >> 5) * 33 + (i2 & 31)] = wreg2;
        int i3 = t + 768;  ws4[(i3 >> 5) * 33 + (i3 & 31)] = wreg3;
        int i4 = t + 1024; ws4[(i4 >> 5) * 33 + (i4 & 31)] = wreg4;
        int i5 = t + 1280; ws4[(i5 >> 5) * 33 + (i5 & 31)] = wreg5;
    }
    __syncthreads();
    int tx = t & 15, ty = t >> 4;
    const float4* ua = us4 + (ty * 2) * 33;
    const float4* ub = ua + 33;
    const float4* w0p = ws4 + (tx * 3) * 33;
    const float4* w1p = w0p + 33;
    const float4* w2p = w0p + 66;
    float acc[2][3] = {};
#pragma unroll 4
    for (int kq = 0; kq < 32; ++kq) {
        float4 u0 = ua[kq], u1 = ub[kq];
        float4 w0 = w0p[kq], w1 = w1p[kq], w2 = w2p[kq];
        acc[0][0] = fmaf(u0.x, w0.x, acc[0][0]); acc[0][0] = fmaf(u0.y, w0.y, acc[0][0]);
        acc[0][0] = fmaf(u0.z, w0.z, acc[0][0]); acc[0][0] = fmaf(u0.w, w0.w, acc[0][0]);
        acc[0][1] = fmaf(u0.x, w1.x, acc[0][1]); acc[0][1] = fmaf(u0.y, w1.y, acc[0][1]);
        acc[0][1] = fmaf(u0.z, w1.z, acc[0][1]); acc[0][1] = fmaf(u0.w, w1.w, acc[0][1]);
        acc[0][2] = fmaf(u0.x, w2.x, acc[0][2]); acc[0][2] = fmaf(u0.y, w2.y, acc[0][2]);
        acc[0][2] = fmaf(u0.z, w2.z, acc[0][2]); acc[0][2] = fmaf(u0.w, w2.w, acc[0][2]);
        acc[1][0] = fmaf(u1.x, w0.x, acc[1][0]); acc[1][0] = fmaf(u1.y, w0.y, acc[1][0]);
        acc[1][0] = fmaf(u1.z, w0.z, acc[1][0]); acc[1][0] = fmaf(u1.w, w0.w, acc[1][0]);
        acc[1][1] = fmaf(u1.x, w1.x, acc[1][1]); acc[1][1] = fmaf(u1.y, w1.y, acc[1][1]);
        acc[1][1] = fmaf(u1.z, w1.z, acc[1][1]); acc[1][1] = fmaf(u1.w, w1.w, acc[1][1]);
        acc[1][2] = fmaf(u1.x, w2.x, acc[1][2]); acc[1][2] = fmaf(u1.y, w2.y, acc[1][2]);
        acc[1][2] = fmaf(u1.z, w2.z, acc[1][2]); acc[1][2] = fmaf(u1.w, w2.w, acc[1][2]);
    }
    float* outp = dbp + (size_t)(r0 + ty * 2) * 192 + kp * 48 + tx * 3;
    outp[0] = acc[0][0]; outp[1] = acc[0][1]; outp[2] = acc[0][2];
    outp[192] = acc[1][0]; outp[193] = acc[1][1]; outp[194] = acc[1][2];
}

// ---------------- dbc reduce + BC extract + delta (512 blocks x 8 rows) ----------------
__global__ __launch_bounds__(256) void k_dbcr(const float* __restrict__ dbp,
                                              const float* __restrict__ dtw,
                                              const float* __restrict__ dtb,
                                              float* __restrict__ delta,
                                              float* __restrict__ BC) {
    __shared__ float dbl[8][NXP];
    int t = threadIdx.x;
    int r0 = blockIdx.x * 8;
    if (t < 128) {
        int r = t >> 4, c3 = (t & 15) * 3;
        const float* pp = dbp + (size_t)(r0 + r) * 192 + c3;
#pragma unroll
        for (int j = 0; j < 3; ++j) {
            float s = pp[j] + pp[48 + j] + pp[96 + j] + pp[144 + j];
            dbl[r][c3 + j] = s;
            int cj = c3 + j;
            if (cj >= 16) BC[(size_t)(r0 + r) * 32 + (cj - 16)] = s;
        }
    }
    __syncthreads();
    {
        int c0 = t * 2;
        float wd0[16], wd1[16];
        const float4* q0 = (const float4*)(dtw + (size_t)c0 * 16);
        const float4* q1 = (const float4*)(dtw + (size_t)(c0 + 1) * 16);
#pragma unroll
        for (int j = 0; j < 4; ++j) { *(float4*)&wd0[j * 4] = q0[j]; *(float4*)&wd1[j * 4] = q1[j]; }
        float bb0 = dtb[c0], bb1 = dtb[c0 + 1];
        for (int r = 0; r < 8; ++r) {
            float s0 = bb0, s1 = bb1;
#pragma unroll
            for (int k = 0; k < 16; ++k) {
                float dv = dbl[r][k];
                s0 = fmaf(dv, wd0[k], s0);
                s1 = fmaf(dv, wd1[k], s1);
            }
            *(float2*)(delta + (size_t)(r0 + r) * DI + c0) =
                make_float2(softplusf_(s0), softplusf_(s1));
        }
    }
}

// ---------------- scan pass A ----------------
__global__ __launch_bounds__(256) void k_scanA(const float* __restrict__ delta,
                                               const float* __restrict__ uc,
                                               const float* __restrict__ BC,
                                               const float* __restrict__ A_log,
                                               float* __restrict__ P,
                                               float* __restrict__ hL) {
    __shared__ float2 du2[CLEN][16];
    __shared__ float  Bl[CLEN][16];
    int bid = blockIdx.x;
    int c = bid & 15, dblk = (bid >> 4) & 31, b = bid >> 9;
    int d0 = dblk * 16, t0 = c * CLEN;
    int t = threadIdx.x;
    {
        int row = t >> 2, hf = (t & 3) * 4;
        size_t rbase = (size_t)(b * LTOT + t0 + row);
        float4 dv = *(const float4*)(delta + rbase * DI + d0 + hf);
        float4 uv = *(const float4*)(uc + rbase * DI + d0 + hf);
        float4* dst = (float4*)&du2[row][hf];
        dst[0] = make_float4(dv.x, uv.x, dv.y, uv.y);
        dst[1] = make_float4(dv.z, uv.z, dv.w, uv.w);
        *(float4*)&Bl[row][hf] = *(const float4*)(BC + rbase * 32 + hf);
    }
    __syncthreads();
    int n = t & 15, dn = t >> 4;
    float Ac = -expf(A_log[(size_t)(d0 + dn) * DS + n]);
    float h = 0.f, Pp = 1.f;
#pragma unroll 8
    for (int k = 0; k < CLEN; ++k) {
        float2 du = du2[k][dn];
        float Bv = Bl[k][n];
        float a = expf(du.x * Ac);
        Pp *= a;
        h = fmaf(a, h, du.x * du.y * Bv);
    }
    size_t idx = ((size_t)(b * NC + c)) * (DI * DS) + (size_t)d0 * DS + t;
    P[idx] = Pp;
    hL[idx] = h;
}

// ---------------- scan pass C (ytmp LDS reduce; Hin loads prefetched after barrier) ---
__global__ __launch_bounds__(256) void k_scanC(const float* __restrict__ delta,
                                               const float* __restrict__ uc,
                                               const float* __restrict__ BC,
                                               const float* __restrict__ A_log,
                                               const float* __restrict__ P,
                                               const float* __restrict__ hL,
                                               const float* __restrict__ Dp,
                                               const float* __restrict__ xz,
                                               unsigned short* __restrict__ yh,
                                               unsigned short* __restrict__ yl) {
    __shared__ float2 du2[CLEN][16];
    __shared__ float2 bc2[CLEN][16];
    __shared__ float  zs[CLEN][16];
    __shared__ float  ytmp[16][16][20];
    int bid = blockIdx.x;
    int c = bid & 15, dblk = (bid >> 4) & 31, b = bid >> 9;
    int d0 = dblk * 16, t0 = c * CLEN;
    int t = threadIdx.x;
    {
        int row = t >> 2, hf = (t & 3) * 4;
        size_t rbase = (size_t)(b * LTOT + t0 + row);
        float4 dv = *(const float4*)(delta + rbase * DI + d0 + hf);
        float4 uv = *(const float4*)(uc + rbase * DI + d0 + hf);
        float4* dst = (float4*)&du2[row][hf];
        dst[0] = make_float4(dv.x, uv.x, dv.y, uv.y);
        dst[1] = make_float4(dv.z, uv.z, dv.w, uv.w);
        float4 bv = *(const float4*)(BC + rbase * 32 + hf);
        float4 cv = *(const float4*)(BC + rbase * 32 + 16 + hf);
        float4* bdst = (float4*)&bc2[row][hf];
        bdst[0] = make_float4(bv.x, cv.x, bv.y, cv.y);
        bdst[1] = make_float4(bv.z, cv.z, bv.w, cv.w);
        *(float4*)&zs[row][hf] = *(const float4*)(xz + rbase * 1024 + 512 + d0 + hf);
    }
    __syncthreads();
    int n = t & 15, dn = t >> 4;
    float Ac = -expf(A_log[(size_t)(d0 + dn) * DS + n]);
    // Hin: fully-unrolled guarded prefetch (independent loads), then exact-order chain
    float Hin = 0.f;
    {
        float pv[15], hv[15];
#pragma unroll
        for (int cc = 0; cc < 15; ++cc) {
            pv[cc] = 0.f; hv[cc] = 0.f;
            if (cc < c) {
                size_t idx = ((size_t)(b * NC + cc)) * (DI * DS) + (size_t)d0 * DS + t;
                pv[cc] = P[idx];
                hv[cc] = hL[idx];
            }
        }
#pragma unroll
        for (int cc = 0; cc < 15; ++cc) {
            if (cc < c) Hin = fmaf(pv[cc], Hin, hv[cc]);
        }
    }
    float h = Hin;
    int rdn = t & 15, rk = t >> 4;
    float DpV = Dp[d0 + rdn];
    for (int s = 0; s < CLEN / 16; ++s) {
#pragma unroll
        for (int kk = 0; kk < 16; ++kk) {
            int k = s * 16 + kk;
            float2 du = du2[k][dn];
            float2 bc = bc2[k][n];
            float a = expf(du.x * Ac);
            h = fmaf(a, h, du.x * du.y * bc.x);
            ytmp[kk][dn][n] = h * bc.y;
        }
        __syncthreads();
        {
            const float* rowp = &ytmp[rk][rdn][0];
            float4 v0 = *(const float4*)(rowp + 0);
            float4 v1 = *(const float4*)(rowp + 4);
            float4 v2 = *(const float4*)(rowp + 8);
            float4 v3 = *(const float4*)(rowp + 12);
            float y = ((v0.x + v0.y) + (v0.z + v0.w)) + ((v1.x + v1.y) + (v1.z + v1.w))
                    + ((v2.x + v2.y) + (v2.z + v2.w)) + ((v3.x + v3.y) + (v3.z + v3.w));
            float uu = du2[s * 16 + rk][rdn].y;
            float z = zs[s * 16 + rk][rdn];
            size_t rb2 = (size_t)(b * LTOT + t0 + s * 16 + rk);
            float val = fmaf(uu, DpV, y) * siluf_(z);
            unsigned short vh, vl; split16(val, vh, vl);
            size_t fa = fragAddr((int)rb2, d0 + rdn, 512);
            yh[fa] = vh; yl[fa] = vl;
        }
        __syncthreads();
    }
}

// ---------------- gemm_out (MFMA, fragment-streamed, depth-2, 1024 blocks x 32x128) ----
__global__ __launch_bounds__(256) void k_gemm_out(const unsigned short* __restrict__ Ahp,
                                                  const unsigned short* __restrict__ Alp,
                                                  const unsigned short* __restrict__ Bhp,
                                                  const unsigned short* __restrict__ Blp,
                                                  float* __restrict__ p01,
                                                  float* __restrict__ p23) {
    int t = threadIdx.x;
    int bx = blockIdx.x & 1;               // 128-col block
    int by = (blockIdx.x >> 1) & 127;      // 32-row block
    int kp = blockIdx.x >> 8;              // K=128 slice
    int lane = t & 63, wid = t >> 6;
    int fr = lane & 31, fg = lane >> 5;
    int rt = by;
    int ct = bx * 4 + wid;                 // 4 coltiles of 32, one per wave
    const half8* pAh = (const half8*)Ahp + (size_t)rt * 2048 + (size_t)kp * 512 + lane;
    const half8* pAl = (const half8*)Alp + (size_t)rt * 2048 + (size_t)kp * 512 + lane;
    const half8* pBh = (const half8*)Bhp + (size_t)ct * 2048 + (size_t)kp * 512 + lane;
    const half8* pBl = (const half8*)Blp + (size_t)ct * 2048 + (size_t)kp * 512 + lane;
    f32x16 acc = {};
    half8 ah0 = pAh[0],  al0 = pAl[0],  bh0 = pBh[0],  bl0 = pBl[0];
    half8 ah1 = pAh[64], al1 = pAl[64], bh1 = pBh[64], bl1 = pBl[64];
#pragma unroll
    for (int kt = 0; kt < 8; kt += 2) {
        half8 nah, nal, nbh, nbl;
        if (kt + 2 < 8) {
            int o = (kt + 2) * 64;
            nah = pAh[o]; nal = pAl[o]; nbh = pBh[o]; nbl = pBl[o];
        }
        acc = __builtin_amdgcn_mfma_f32_32x32x16_f16(ah0, bh0, acc, 0, 0, 0);
        acc = __builtin_amdgcn_mfma_f32_32x32x16_f16(ah0, bl0, acc, 0, 0, 0);
        acc = __builtin_amdgcn_mfma_f32_32x32x16_f16(al0, bh0, acc, 0, 0, 0);
        if (kt + 2 < 8) { ah0 = nah; al0 = nal; bh0 = nbh; bl0 = nbl; }
        half8 mah, mal, mbh, mbl;
        if (kt + 3 < 8) {
            int o = (kt + 3) * 64;
            mah = pAh[o]; mal = pAl[o]; mbh = pBh[o]; mbl = pBl[o];
        }
        acc = __builtin_amdgcn_mfma_f32_32x32x16_f16(ah1, bh1, acc, 0, 0, 0);
        acc = __builtin_amdgcn_mfma_f32_32x32x16_f16(ah1, bl1, acc, 0, 0, 0);
        acc = __builtin_amdgcn_mfma_f32_32x32x16_f16(al1, bh1, acc, 0, 0, 0);
        if (kt + 3 < 8) { ah1 = mah; al1 = mal; bh1 = mbh; bl1 = mbl; }
    }
    float* pbase = (kp < 2 ? p01 : p23) + (size_t)(kp & 1) * (ROWS * DM);
    float* Cp = pbase + (size_t)(by * 32) * DM + bx * 128 + wid * 32;
#pragma unroll
    for (int reg = 0; reg < 16; ++reg) {
        int row = (reg & 3) + 8 * (reg >> 2) + 4 * fg;
        Cp[(size_t)row * DM + fr] = acc[reg];
    }
}

// ---------------- layernorm + residual (sums 4 gemm_out partials, emits h16) --------
__global__ __launch_bounds__(256) void k_ln_res(const float* __restrict__ p01,
                                                const float* __restrict__ p23,
                                                const float* __restrict__ g,
                                                const float* __restrict__ bb,
                                                float* __restrict__ h,
                                                unsigned short* __restrict__ hh,
                                                unsigned short* __restrict__ hl) {
    __shared__ float scratch[4];
    int r = blockIdx.x, t = threadIdx.x;
    size_t idx = (size_t)r * DM + t;
    float v = p01[idx] + p01[idx + (size_t)ROWS * DM] + p23[idx] + p23[idx + (size_t)ROWS * DM];
    float s = v;
#pragma unroll
    for (int m = 32; m >= 1; m >>= 1) s += __shfl_xor(s, m, 64);
    if ((t & 63) == 0) scratch[t >> 6] = s;
    __syncthreads();
    float mu = (scratch[0] + scratch[1] + scratch[2] + scratch[3]) * (1.f / DM);
    __syncthreads();
    float d = v - mu;
    float s2 = d * d;
#pragma unroll
    for (int m = 32; m >= 1; m >>= 1) s2 += __shfl_xor(s2, m, 64);
    if ((t & 63) == 0) scratch[t >> 6] = s2;
    __syncthreads();
    float var = (scratch[0] + scratch[1] + scratch[2] + scratch[3]) * (1.f / DM);
    float rstd = 1.f / sqrtf(var + 1e-5f);
    float nv = h[idx] + d * rstd * g[t] + bb[t];
    h[idx] = nv;
    unsigned short vh, vl; split16(nv, vh, vl);
    size_t fa = fragAddr(r, t, 256);
    hh[fa] = vh; hl[fa] = vl;
}

// ---------------- mean over L (partials, deterministic) ----------------
__global__ __launch_bounds__(256) void k_meanp(const float* __restrict__ h,
                                               float* __restrict__ part) {
    int bid = blockIdx.x;
    int b = bid >> 3, g = bid & 7;
    int t = threadIdx.x;
    float s = 0.f;
    for (int k = 0; k < 128; ++k)
        s += h[(size_t)(b * LTOT + g * 128 + k) * DM + t];
    part[(size_t)bid * DM + t] = s;
}

// ---------------- head (float4 weight streams, same FMA order) ----------------
__global__ __launch_bounds__(256) void k_head(const float* __restrict__ part,
                                              const float* __restrict__ w1,
                                              const float* __restrict__ b1,
                                              const float* __restrict__ w2,
                                              const float* __restrict__ b2,
                                              float* __restrict__ out) {
    __shared__ float pl[DM], hl[DM];
    int b = blockIdx.x, t = threadIdx.x;
    float s = 0.f;
    for (int g = 0; g < 8; ++g) s += part[(size_t)(b * 8 + g) * DM + t];
    pl[t] = s * (1.f / LTOT);
    __syncthreads();
    float a = b1[t];
    const float4* w1p = (const float4*)(w1 + (size_t)t * DM);
    for (int k = 0; k < DM / 4; ++k) {
        float4 w = w1p[k];
        a = fmaf(pl[k * 4 + 0], w.x, a);
        a = fmaf(pl[k * 4 + 1], w.y, a);
        a = fmaf(pl[k * 4 + 2], w.z, a);
        a = fmaf(pl[k * 4 + 3], w.w, a);
    }
    hl[t] = fmaxf(a, 0.f);
    __syncthreads();
    if (t < NH) {
        float o = b2[t];
        const float4* w2p = (const float4*)(w2 + (size_t)t * DM);
        for (int k = 0; k < DM / 4; ++k) {
            float4 w = w2p[k];
            o = fmaf(hl[k * 4 + 0], w.x, o);
            o = fmaf(hl[k * 4 + 1], w.y, o);
            o = fmaf(hl[k * 4 + 2], w.z, o);
            o = fmaf(hl[k * 4 + 3], w.w, o);
        }
        out[b * NH + t] = o;
    }
}

extern "C" void kernel_launch(void* const* d_in, const int* in_sizes, int n_in,
                              void* d_out, int out_size, void* d_ws, size_t ws_size,
                              hipStream_t stream) {
    const float* x        = (const float*)d_in[0];
    const float* proj_w   = (const float*)d_in[1];
    const float* proj_b   = (const float*)d_in[2];
    const float* inproj_w = (const float*)d_in[3];
    const float* conv_w   = (const float*)d_in[4];
    const float* conv_b   = (const float*)d_in[5];
    const float* xproj_w  = (const float*)d_in[6];
    const float* dtproj_w = (const float*)d_in[7];
    const float* dtproj_b = (const float*)d_in[8];
    const float* A_log    = (const float*)d_in[9];
    const float* Dp       = (const float*)d_in[10];
    const float* outproj_w= (const float*)d_in[11];
    const float* ln_g     = (const float*)d_in[12];
    const float* ln_b     = (const float*)d_in[13];
    const float* head_w1  = (const float*)d_in[14];
    const float* head_b1  = (const float*)d_in[15];
    const float* head_w2  = (const float*)d_in[16];
    const float* head_b2  = (const float*)d_in[17];

    float* ws    = (float*)d_ws;
    float* h     = ws;                    // 1,048,576 f
    float* xz    = h + 1048576;           // 4,194,304 f
    float* uc    = xz + 4194304;          // 2,097,152 f
    float* dbp   = uc + 2097152;          //   786,432 f (4096*192 dbc partials)
    float* delta = dbp + 786432;          // 2,097,152 f
    float* BC    = delta + 2097152;       //   131,072 f
    float* Pbuf  = BC + 131072;           //   524,288 f
    float* hLbuf = Pbuf + 524288;         //   524,288 f
    float* p01   = hLbuf + 524288;        // 2,097,152 f (gemm_out partials 0,1)
    float* p23   = p01 + 2097152;         // 2,097,152 f (gemm_out partials 2,3)
    float* part  = p23 + 2097152;         //     8,192 f
    unsigned short* h_hi  = (unsigned short*)(part + 8192);  // 4096*256 ush (fragment order)
    unsigned short* h_lo  = h_hi + 1048576;
    unsigned short* y_hi  = h_lo + 1048576;                  // 4096*512 ush (fragment order)
    unsigned short* y_lo  = y_hi + 2097152;
    unsigned short* iw_hi = y_lo + 2097152;                  // 4*1024*256 ush (fragment order)
    unsigned short* iw_lo = iw_hi + 1048576;
    unsigned short* ow_hi = iw_lo + 1048576;                 // 4*256*512 ush (fragment order)
    unsigned short* ow_lo = ow_hi + 524288;

    k_init<<<1792, 256, 0, stream>>>(x, proj_w, proj_b, inproj_w, outproj_w,
                                     h, h_hi, h_lo, iw_hi, iw_lo, ow_hi, ow_lo);

    for (int i = 0; i < NLAY; ++i) {
        const float* cwi  = conv_w + (size_t)i * DI * 4;
        const float* cbi  = conv_b + (size_t)i * DI;
        const float* xpw  = xproj_w + (size_t)i * NXP * DI;
        const float* dtw  = dtproj_w + (size_t)i * DI * DTRN;
        const float* dtb  = dtproj_b + (size_t)i * DI;
        const float* Ali  = A_log + (size_t)i * DI * DS;
        const float* Dpi  = Dp + (size_t)i * DI;
        const float* gi   = ln_g + (size_t)i * DM;
        const float* bi   = ln_b + (size_t)i * DM;

        k_gemm_xz<<<1024, 256, 0, stream>>>(h_hi, h_lo,
                                            iw_hi + (size_t)i * 262144, iw_lo + (size_t)i * 262144, xz);
        k_dbcp<<<512, 256, 0, stream>>>(xz, cwi, cbi, xpw, uc, dbp);
        k_dbcr<<<ROWS / 8, 256, 0, stream>>>(dbp, dtw, dtb, delta, BC);
        k_scanA<<<BB * 32 * NC, 256, 0, stream>>>(delta, uc, BC, Ali, Pbuf, hLbuf);
        k_scanC<<<BB * 32 * NC, 256, 0, stream>>>(delta, uc, BC, Ali, Pbuf, hLbuf, Dpi, xz, y_hi, y_lo);
        k_gemm_out<<<1024, 256, 0, stream>>>(y_hi, y_lo,
                                             ow_hi + (size_t)i * 131072, ow_lo + (size_t)i * 131072,
                                             p01, p23);
        k_ln_res<<<ROWS, 256, 0, stream>>>(p01, p23, gi, bi, h, h_hi, h_lo);
    }

    k_meanp<<<32, 256, 0, stream>>>(h, part);
    k_head<<<BB, 256, 0, stream>>>(part, head_w1, head_b1, head_w2, head_b2, (float*)d_out);
}

// Round 15
// 440.142 us; speedup vs baseline: 1.0305x; 1.0222x over previous
//
#include <hip/hip_runtime.h>
#include <hip/hip_fp16.h>
#include <math.h>

// Problem dims
#define LTOT 1024
#define BB   4
#define F_IN 32
#define DM   256
#define DI   512
#define DS   16
#define DTRN 16
#define NXP  48         // DTR + 2*DS
#define NLAY 4
#define NH   4
#define NC   16         // scan chunks
#define CLEN 64         // L / NC
#define ROWS (BB*LTOT)  // 4096

typedef _Float16 half8 __attribute__((ext_vector_type(8)));
typedef float f32x16 __attribute__((ext_vector_type(16)));

__device__ __forceinline__ float siluf_(float x) { return x / (1.0f + expf(-x)); }
__device__ __forceinline__ float softplusf_(float x) {
    if (x > 20.f) return x;
    if (x < -20.f) return expf(x);
    return log1pf(expf(x));
}

// fp16 2-piece split: x ~= hi + lo with ~22-bit combined mantissa
__device__ __forceinline__ void split16(float x, unsigned short& hi, unsigned short& lo) {
    __half h = __float2half(x);
    hi = *(unsigned short*)&h;
    float r = x - __half2float(h);
    __half l = __float2half(r);
    lo = *(unsigned short*)&l;
}

// MFMA fragment-order address for element (r, k) of a matrix with k-dim Kd.
__device__ __forceinline__ size_t fragAddr(int r, int k, int Kd) {
    return ((size_t)((r >> 5) * (Kd >> 4) + (k >> 4)) << 9)
         + (size_t)(((((k >> 3) & 1) << 5) + (r & 31)) * 8 + (k & 7));
}

// ---------------- init: fused weight-split->fragment (blocks 0..1535) + proj (1536..1791) ----
__global__ __launch_bounds__(256) void k_init(const float* __restrict__ x,
                                              const float* __restrict__ pw,
                                              const float* __restrict__ pb,
                                              const float* __restrict__ inw,
                                              const float* __restrict__ outw,
                                              float* __restrict__ h,
                                              unsigned short* __restrict__ hh,
                                              unsigned short* __restrict__ hl,
                                              unsigned short* __restrict__ iwh,
                                              unsigned short* __restrict__ iwl,
                                              unsigned short* __restrict__ owh,
                                              unsigned short* __restrict__ owl) {
    __shared__ float wl[DM][33];
    __shared__ float xl[16][32];
    int bid = blockIdx.x, t = threadIdx.x;
    if (bid < 1536) {   // ---- weight split into fragment order ----
        int q = bid * 256 + t;
        ushort4 h4, l4;
        if (q < 262144) {                          // inw: 4 layers x 1024 rows x K=256
            float4 v = ((const float4*)inw)[q];
            split16(v.x, h4.x, l4.x); split16(v.y, h4.y, l4.y);
            split16(v.z, h4.z, l4.z); split16(v.w, h4.w, l4.w);
            int row = q >> 6, k0 = (q & 63) * 4;
            int lay = row >> 10, rIn = row & 1023;
            size_t fa = (size_t)lay * 262144 + fragAddr(rIn, k0, 256);
            *(ushort4*)(iwh + fa) = h4;
            *(ushort4*)(iwl + fa) = l4;
        } else {
            int rq = q - 262144;                   // outw: 4 layers x 256 rows x K=512
            float4 v = ((const float4*)outw)[rq];
            split16(v.x, h4.x, l4.x); split16(v.y, h4.y, l4.y);
            split16(v.z, h4.z, l4.z); split16(v.w, h4.w, l4.w);
            int row = rq >> 7, k0 = (rq & 127) * 4;
            int lay = row >> 8, rIn = row & 255;
            size_t fa = (size_t)lay * 131072 + fragAddr(rIn, k0, 512);
            *(ushort4*)(owh + fa) = h4;
            *(ushort4*)(owl + fa) = l4;
        }
        return;
    }
    // ---- proj: h = x @ proj_w.T + proj_b (+ fragment-order fp16 emit) ----
    int r0 = (bid - 1536) * 16;
    for (int i = t; i < DM * 32 / 4; i += 256) {
        float4 v = ((const float4*)pw)[i];
        int c = i / 8, k = (i % 8) * 4;
        wl[c][k] = v.x; wl[c][k + 1] = v.y; wl[c][k + 2] = v.z; wl[c][k + 3] = v.w;
    }
    for (int i = t; i < 16 * 32 / 4; i += 256) {
        float4 v = ((const float4*)(x + (size_t)r0 * F_IN))[i];
        int r = i / 8, k = (i % 8) * 4;
        xl[r][k] = v.x; xl[r][k + 1] = v.y; xl[r][k + 2] = v.z; xl[r][k + 3] = v.w;
    }
    __syncthreads();
    int c = t;
    float bias = pb[c];
    float acc[16];
#pragma unroll
    for (int r = 0; r < 16; ++r) acc[r] = bias;
    for (int k = 0; k < 32; ++k) {
        float w = wl[c][k];
#pragma unroll
        for (int r = 0; r < 16; ++r) acc[r] = fmaf(xl[r][k], w, acc[r]);
    }
#pragma unroll
    for (int r = 0; r < 16; ++r) {
        int rr = r0 + r;
        h[(size_t)rr * DM + c] = acc[r];
        unsigned short vh, vl; split16(acc[r], vh, vl);
        size_t fa = fragAddr(rr, c, 256);
        hh[fa] = vh; hl[fa] = vl;
    }
}

// ---------------- gemm_xz (MFMA, fragment-streamed, depth-2, 1024 blocks x 64x64) -----
__global__ __launch_bounds__(256) void k_gemm_xz(const unsigned short* __restrict__ Ahp,
                                                 const unsigned short* __restrict__ Alp,
                                                 const unsigned short* __restrict__ Bhp,
                                                 const unsigned short* __restrict__ Blp,
                                                 float* __restrict__ C) {
    int t = threadIdx.x;
    int bx = blockIdx.x & 15;     // colblock of 64
    int by = blockIdx.x >> 4;     // rowblock of 64
    int lane = t & 63, wid = t >> 6;
    int fr = lane & 31, fg = lane >> 5;
    int wr = wid >> 1, wc = wid & 1;
    int rt = by * 2 + wr;
    int ct = bx * 2 + wc;
    const half8* pAh = (const half8*)Ahp + (size_t)rt * 1024 + lane;
    const half8* pAl = (const half8*)Alp + (size_t)rt * 1024 + lane;
    const half8* pBh = (const half8*)Bhp + (size_t)ct * 1024 + lane;
    const half8* pBl = (const half8*)Blp + (size_t)ct * 1024 + lane;
    f32x16 acc = {};
    half8 ah0 = pAh[0],  al0 = pAl[0],  bh0 = pBh[0],  bl0 = pBl[0];
    half8 ah1 = pAh[64], al1 = pAl[64], bh1 = pBh[64], bl1 = pBl[64];
#pragma unroll
    for (int kt = 0; kt < 16; kt += 2) {
        half8 nah, nal, nbh, nbl;
        if (kt + 2 < 16) {
            int o = (kt + 2) * 64;
            nah = pAh[o]; nal = pAl[o]; nbh = pBh[o]; nbl = pBl[o];
        }
        acc = __builtin_amdgcn_mfma_f32_32x32x16_f16(ah0, bh0, acc, 0, 0, 0);
        acc = __builtin_amdgcn_mfma_f32_32x32x16_f16(ah0, bl0, acc, 0, 0, 0);
        acc = __builtin_amdgcn_mfma_f32_32x32x16_f16(al0, bh0, acc, 0, 0, 0);
        if (kt + 2 < 16) { ah0 = nah; al0 = nal; bh0 = nbh; bl0 = nbl; }
        half8 mah, mal, mbh, mbl;
        if (kt + 3 < 16) {
            int o = (kt + 3) * 64;
            mah = pAh[o]; mal = pAl[o]; mbh = pBh[o]; mbl = pBl[o];
        }
        acc = __builtin_amdgcn_mfma_f32_32x32x16_f16(ah1, bh1, acc, 0, 0, 0);
        acc = __builtin_amdgcn_mfma_f32_32x32x16_f16(ah1, bl1, acc, 0, 0, 0);
        acc = __builtin_amdgcn_mfma_f32_32x32x16_f16(al1, bh1, acc, 0, 0, 0);
        if (kt + 3 < 16) { ah1 = mah; al1 = mal; bh1 = mbh; bl1 = mbl; }
    }
    float* Cp = C + (size_t)(by * 64 + wr * 32) * 1024 + bx * 64 + wc * 32;
#pragma unroll
    for (int reg = 0; reg < 16; ++reg) {
        int row = (reg & 3) + 8 * (reg >> 2) + 4 * fg;
        Cp[(size_t)row * 1024 + fr] = acc[reg];
    }
}

// ---------------- dbc partial GEMM (split-K by 4) with fused causal conv+silu --------
// R12-proven form: 512 blocks x 32 rows, early weight-issue.
__global__ __launch_bounds__(256) void k_dbcp(const float* __restrict__ xz,
                                              const float* __restrict__ cw,
                                              const float* __restrict__ cb,
                                              const float* __restrict__ xpw,
                                              float* __restrict__ uc,
                                              float* __restrict__ dbp) {
    __shared__ float us[32][132];
    __shared__ float wsd[48][132];
    int t = threadIdx.x;
    int kp = blockIdx.x & 3;
    int r0 = (blockIdx.x >> 2) * 32;
    int k0 = kp * 128;
    float4* us4 = (float4*)us;
    float4* ws4 = (float4*)wsd;
    float4 wreg0, wreg1, wreg2, wreg3, wreg4, wreg5;
    {
        int i0 = t;            wreg0 = *(const float4*)(xpw + (size_t)(i0 >> 5) * DI + k0 + (i0 & 31) * 4);
        int i1 = t + 256;      wreg1 = *(const float4*)(xpw + (size_t)(i1 >> 5) * DI + k0 + (i1 & 31) * 4);
        int i2 = t + 512;      wreg2 = *(const float4*)(xpw + (size_t)(i2 >> 5) * DI + k0 + (i2 & 31) * 4);
        int i3 = t + 768;      wreg3 = *(const float4*)(xpw + (size_t)(i3 >> 5) * DI + k0 + (i3 & 31) * 4);
        int i4 = t + 1024;     wreg4 = *(const float4*)(xpw + (size_t)(i4 >> 5) * DI + k0 + (i4 & 31) * 4);
        int i5 = t + 1280;     wreg5 = *(const float4*)(xpw + (size_t)(i5 >> 5) * DI + k0 + (i5 & 31) * 4);
    }
#pragma unroll
    for (int j = 0; j < 4; ++j) {
        int i = t + j * 256;
        int r = i >> 5, kq = i & 31;
        int rr = r0 + r, d = k0 + kq * 4;
        int tt = rr & (LTOT - 1);
        float4 acc = make_float4(cb[d], cb[d + 1], cb[d + 2], cb[d + 3]);
#pragma unroll
        for (int k = 0; k < 4; ++k) {
            int ts = tt - 3 + k;
            if (ts < 0) continue;
            float4 u = *(const float4*)(xz + (size_t)(rr - 3 + k) * 1024 + d);
            acc.x = fmaf(u.x, cw[(d + 0) * 4 + k], acc.x);
            acc.y = fmaf(u.y, cw[(d + 1) * 4 + k], acc.y);
            acc.z = fmaf(u.z, cw[(d + 2) * 4 + k], acc.z);
            acc.w = fmaf(u.w, cw[(d + 3) * 4 + k], acc.w);
        }
        acc.x = siluf_(acc.x); acc.y = siluf_(acc.y); acc.z = siluf_(acc.z); acc.w = siluf_(acc.w);
        us4[r * 33 + kq] = acc;
        *(float4*)(uc + (size_t)rr * DI + d) = acc;
    }
    {
        int i0 = t;        ws4[(i0 >> 5) * 33 + (i0 & 31)] = wreg0;
        int i1 = t + 256;  ws4[(i1 >> 5) * 33 + (i1 & 31)] = wreg1;
        int i2 = t + 512;  ws4[(i2 >> 5) * 33 + (i2 & 31)] = wreg2;
        int i3 = t + 768;  ws4[(i3 >> 5) * 33 + (i3 & 31)] = wreg3;
        int i4 = t + 1024; ws4[(i4 >> 5) * 33 + (i4 & 31)] = wreg4;
        int i5 = t + 1280; ws4[(i5 >> 5) * 33 + (i5 & 31)] = wreg5;
    }
    __syncthreads();
    int tx = t & 15, ty = t >> 4;
    const float4* ua = us4 + (ty * 2) * 33;
    const float4* ub = ua + 33;
    const float4* w0p = ws4 + (tx * 3) * 33;
    const float4* w1p = w0p + 33;
    const float4* w2p = w0p + 66;
    float acc[2][3] = {};
#pragma unroll 4
    for (int kq = 0; kq < 32; ++kq) {
        float4 u0 = ua[kq], u1 = ub[kq];
        float4 w0 = w0p[kq], w1 = w1p[kq], w2 = w2p[kq];
        acc[0][0] = fmaf(u0.x, w0.x, acc[0][0]); acc[0][0] = fmaf(u0.y, w0.y, acc[0][0]);
        acc[0][0] = fmaf(u0.z, w0.z, acc[0][0]); acc[0][0] = fmaf(u0.w, w0.w, acc[0][0]);
        acc[0][1] = fmaf(u0.x, w1.x, acc[0][1]); acc[0][1] = fmaf(u0.y, w1.y, acc[0][1]);
        acc[0][1] = fmaf(u0.z, w1.z, acc[0][1]); acc[0][1] = fmaf(u0.w, w1.w, acc[0][1]);
        acc[0][2] = fmaf(u0.x, w2.x, acc[0][2]); acc[0][2] = fmaf(u0.y, w2.y, acc[0][2]);
        acc[0][2] = fmaf(u0.z, w2.z, acc[0][2]); acc[0][2] = fmaf(u0.w, w2.w, acc[0][2]);
        acc[1][0] = fmaf(u1.x, w0.x, acc[1][0]); acc[1][0] = fmaf(u1.y, w0.y, acc[1][0]);
        acc[1][0] = fmaf(u1.z, w0.z, acc[1][0]); acc[1][0] = fmaf(u1.w, w0.w, acc[1][0]);
        acc[1][1] = fmaf(u1.x, w1.x, acc[1][1]); acc[1][1] = fmaf(u1.y, w1.y, acc[1][1]);
        acc[1][1] = fmaf(u1.z, w1.z, acc[1][1]); acc[1][1] = fmaf(u1.w, w1.w, acc[1][1]);
        acc[1][2] = fmaf(u1.x, w2.x, acc[1][2]); acc[1][2] = fmaf(u1.y, w2.y, acc[1][2]);
        acc[1][2] = fmaf(u1.z, w2.z, acc[1][2]); acc[1][2] = fmaf(u1.w, w2.w, acc[1][2]);
    }
    float* outp = dbp + (size_t)(r0 + ty * 2) * 192 + kp * 48 + tx * 3;
    outp[0] = acc[0][0]; outp[1] = acc[0][1]; outp[2] = acc[0][2];
    outp[192] = acc[1][0]; outp[193] = acc[1][1]; outp[194] = acc[1][2];
}

// ---------------- dbc reduce + BC extract + delta (512 blocks x 8 rows) ----------------
__global__ __launch_bounds__(256) void k_dbcr(const float* __restrict__ dbp,
                                              const float* __restrict__ dtw,
                                              const float* __restrict__ dtb,
                                              float* __restrict__ delta,
                                              float* __restrict__ BC) {
    __shared__ float dbl[8][NXP];
    int t = threadIdx.x;
    int r0 = blockIdx.x * 8;
    if (t < 128) {
        int r = t >> 4, c3 = (t & 15) * 3;
        const float* pp = dbp + (size_t)(r0 + r) * 192 + c3;
#pragma unroll
        for (int j = 0; j < 3; ++j) {
            float s = pp[j] + pp[48 + j] + pp[96 + j] + pp[144 + j];
            dbl[r][c3 + j] = s;
            int cj = c3 + j;
            if (cj >= 16) BC[(size_t)(r0 + r) * 32 + (cj - 16)] = s;
        }
    }
    __syncthreads();
    {
        int c0 = t * 2;
        float wd0[16], wd1[16];
        const float4* q0 = (const float4*)(dtw + (size_t)c0 * 16);
        const float4* q1 = (const float4*)(dtw + (size_t)(c0 + 1) * 16);
#pragma unroll
        for (int j = 0; j < 4; ++j) { *(float4*)&wd0[j * 4] = q0[j]; *(float4*)&wd1[j * 4] = q1[j]; }
        float bb0 = dtb[c0], bb1 = dtb[c0 + 1];
        for (int r = 0; r < 8; ++r) {
            float s0 = bb0, s1 = bb1;
#pragma unroll
            for (int k = 0; k < 16; ++k) {
                float dv = dbl[r][k];
                s0 = fmaf(dv, wd0[k], s0);
                s1 = fmaf(dv, wd1[k], s1);
            }
            *(float2*)(delta + (size_t)(r0 + r) * DI + c0) =
                make_float2(softplusf_(s0), softplusf_(s1));
        }
    }
}

// ---------------- scan pass A (chunk 15 skipped: its P/hL are never consumed) ---------
__global__ __launch_bounds__(256) void k_scanA(const float* __restrict__ delta,
                                               const float* __restrict__ uc,
                                               const float* __restrict__ BC,
                                               const float* __restrict__ A_log,
                                               float* __restrict__ P,
                                               float* __restrict__ hL) {
    __shared__ float2 du2[CLEN][16];
    __shared__ float  Bl[CLEN][16];
    int bid = blockIdx.x;
    int c = bid & 15, dblk = (bid >> 4) & 31, b = bid >> 9;
    if (c == 15) return;   // chunk 15 outputs unused by scanC (reads cc < c <= 14)
    int d0 = dblk * 16, t0 = c * CLEN;
    int t = threadIdx.x;
    {
        int row = t >> 2, hf = (t & 3) * 4;
        size_t rbase = (size_t)(b * LTOT + t0 + row);
        float4 dv = *(const float4*)(delta + rbase * DI + d0 + hf);
        float4 uv = *(const float4*)(uc + rbase * DI + d0 + hf);
        float4* dst = (float4*)&du2[row][hf];
        dst[0] = make_float4(dv.x, uv.x, dv.y, uv.y);
        dst[1] = make_float4(dv.z, uv.z, dv.w, uv.w);
        *(float4*)&Bl[row][hf] = *(const float4*)(BC + rbase * 32 + hf);
    }
    __syncthreads();
    int n = t & 15, dn = t >> 4;
    float Ac = -expf(A_log[(size_t)(d0 + dn) * DS + n]);
    float h = 0.f, Pp = 1.f;
#pragma unroll 8
    for (int k = 0; k < CLEN; ++k) {
        float2 du = du2[k][dn];
        float Bv = Bl[k][n];
        float a = expf(du.x * Ac);
        Pp *= a;
        h = fmaf(a, h, du.x * du.y * Bv);
    }
    size_t idx = ((size_t)(b * NC + c)) * (DI * DS) + (size_t)d0 * DS + t;
    P[idx] = Pp;
    hL[idx] = h;
}

// ---------------- scan pass C (ytmp LDS reduce; Hin loads prefetched after barrier) ---
__global__ __launch_bounds__(256) void k_scanC(const float* __restrict__ delta,
                                               const float* __restrict__ uc,
                                               const float* __restrict__ BC,
                                               const float* __restrict__ A_log,
                                               const float* __restrict__ P,
                                               const float* __restrict__ hL,
                                               const float* __restrict__ Dp,
                                               const float* __restrict__ xz,
                                               unsigned short* __restrict__ yh,
                                               unsigned short* __restrict__ yl) {
    __shared__ float2 du2[CLEN][16];
    __shared__ float2 bc2[CLEN][16];
    __shared__ float  zs[CLEN][16];
    __shared__ float  ytmp[16][16][20];
    int bid = blockIdx.x;
    int c = bid & 15, dblk = (bid >> 4) & 31, b = bid >> 9;
    int d0 = dblk * 16, t0 = c * CLEN;
    int t = threadIdx.x;
    {
        int row = t >> 2, hf = (t & 3) * 4;
        size_t rbase = (size_t)(b * LTOT + t0 + row);
        float4 dv = *(const float4*)(delta + rbase * DI + d0 + hf);
        float4 uv = *(const float4*)(uc + rbase * DI + d0 + hf);
        float4* dst = (float4*)&du2[row][hf];
        dst[0] = make_float4(dv.x, uv.x, dv.y, uv.y);
        dst[1] = make_float4(dv.z, uv.z, dv.w, uv.w);
        float4 bv = *(const float4*)(BC + rbase * 32 + hf);
        float4 cv = *(const float4*)(BC + rbase * 32 + 16 + hf);
        float4* bdst = (float4*)&bc2[row][hf];
        bdst[0] = make_float4(bv.x, cv.x, bv.y, cv.y);
        bdst[1] = make_float4(bv.z, cv.z, bv.w, cv.w);
        *(float4*)&zs[row][hf] = *(const float4*)(xz + rbase * 1024 + 512 + d0 + hf);
    }
    __syncthreads();
    int n = t & 15, dn = t >> 4;
    float Ac = -expf(A_log[(size_t)(d0 + dn) * DS + n]);
    // Hin: fully-unrolled guarded prefetch (independent loads), then exact-order chain
    float Hin = 0.f;
    {
        float pv[15], hv[15];
#pragma unroll
        for (int cc = 0; cc < 15; ++cc) {
            pv[cc] = 0.f; hv[cc] = 0.f;
            if (cc < c) {
                size_t idx = ((size_t)(b * NC + cc)) * (DI * DS) + (size_t)d0 * DS + t;
                pv[cc] = P[idx];
                hv[cc] = hL[idx];
            }
        }
#pragma unroll
        for (int cc = 0; cc < 15; ++cc) {
            if (cc < c) Hin = fmaf(pv[cc], Hin, hv[cc]);
        }
    }
    float h = Hin;
    int rdn = t & 15, rk = t >> 4;
    float DpV = Dp[d0 + rdn];
    for (int s = 0; s < CLEN / 16; ++s) {
#pragma unroll
        for (int kk = 0; kk < 16; ++kk) {
            int k = s * 16 + kk;
            float2 du = du2[k][dn];
            float2 bc = bc2[k][n];
            float a = expf(du.x * Ac);
            h = fmaf(a, h, du.x * du.y * bc.x);
            ytmp[kk][dn][n] = h * bc.y;
        }
        __syncthreads();
        {
            const float* rowp = &ytmp[rk][rdn][0];
            float4 v0 = *(const float4*)(rowp + 0);
            float4 v1 = *(const float4*)(rowp + 4);
            float4 v2 = *(const float4*)(rowp + 8);
            float4 v3 = *(const float4*)(rowp + 12);
            float y = ((v0.x + v0.y) + (v0.z + v0.w)) + ((v1.x + v1.y) + (v1.z + v1.w))
                    + ((v2.x + v2.y) + (v2.z + v2.w)) + ((v3.x + v3.y) + (v3.z + v3.w));
            float uu = du2[s * 16 + rk][rdn].y;
            float z = zs[s * 16 + rk][rdn];
            size_t rb2 = (size_t)(b * LTOT + t0 + s * 16 + rk);
            float val = fmaf(uu, DpV, y) * siluf_(z);
            unsigned short vh, vl; split16(val, vh, vl);
            size_t fa = fragAddr((int)rb2, d0 + rdn, 512);
            yh[fa] = vh; yl[fa] = vl;
        }
        __syncthreads();
    }
}

// ---------------- gemm_out (MFMA, fragment-streamed, depth-2, 1024 blocks x 32x128) ----
__global__ __launch_bounds__(256) void k_gemm_out(const unsigned short* __restrict__ Ahp,
                                                  const unsigned short* __restrict__ Alp,
                                                  const unsigned short* __restrict__ Bhp,
                                                  const unsigned short* __restrict__ Blp,
                                                  float* __restrict__ p01,
                                                  float* __restrict__ p23) {
    int t = threadIdx.x;
    int bx = blockIdx.x & 1;               // 128-col block
    int by = (blockIdx.x >> 1) & 127;      // 32-row block
    int kp = blockIdx.x >> 8;              // K=128 slice
    int lane = t & 63, wid = t >> 6;
    int fr = lane & 31, fg = lane >> 5;
    int rt = by;
    int ct = bx * 4 + wid;                 // 4 coltiles of 32, one per wave
    const half8* pAh = (const half8*)Ahp + (size_t)rt * 2048 + (size_t)kp * 512 + lane;
    const half8* pAl = (const half8*)Alp + (size_t)rt * 2048 + (size_t)kp * 512 + lane;
    const half8* pBh = (const half8*)Bhp + (size_t)ct * 2048 + (size_t)kp * 512 + lane;
    const half8* pBl = (const half8*)Blp + (size_t)ct * 2048 + (size_t)kp * 512 + lane;
    f32x16 acc = {};
    half8 ah0 = pAh[0],  al0 = pAl[0],  bh0 = pBh[0],  bl0 = pBl[0];
    half8 ah1 = pAh[64], al1 = pAl[64], bh1 = pBh[64], bl1 = pBl[64];
#pragma unroll
    for (int kt = 0; kt < 8; kt += 2) {
        half8 nah, nal, nbh, nbl;
        if (kt + 2 < 8) {
            int o = (kt + 2) * 64;
            nah = pAh[o]; nal = pAl[o]; nbh = pBh[o]; nbl = pBl[o];
        }
        acc = __builtin_amdgcn_mfma_f32_32x32x16_f16(ah0, bh0, acc, 0, 0, 0);
        acc = __builtin_amdgcn_mfma_f32_32x32x16_f16(ah0, bl0, acc, 0, 0, 0);
        acc = __builtin_amdgcn_mfma_f32_32x32x16_f16(al0, bh0, acc, 0, 0, 0);
        if (kt + 2 < 8) { ah0 = nah; al0 = nal; bh0 = nbh; bl0 = nbl; }
        half8 mah, mal, mbh, mbl;
        if (kt + 3 < 8) {
            int o = (kt + 3) * 64;
            mah = pAh[o]; mal = pAl[o]; mbh = pBh[o]; mbl = pBl[o];
        }
        acc = __builtin_amdgcn_mfma_f32_32x32x16_f16(ah1, bh1, acc, 0, 0, 0);
        acc = __builtin_amdgcn_mfma_f32_32x32x16_f16(ah1, bl1, acc, 0, 0, 0);
        acc = __builtin_amdgcn_mfma_f32_32x32x16_f16(al1, bh1, acc, 0, 0, 0);
        if (kt + 3 < 8) { ah1 = mah; al1 = mal; bh1 = mbh; bl1 = mbl; }
    }
    float* pbase = (kp < 2 ? p01 : p23) + (size_t)(kp & 1) * (ROWS * DM);
    float* Cp = pbase + (size_t)(by * 32) * DM + bx * 128 + wid * 32;
#pragma unroll
    for (int reg = 0; reg < 16; ++reg) {
        int row = (reg & 3) + 8 * (reg >> 2) + 4 * fg;
        Cp[(size_t)row * DM + fr] = acc[reg];
    }
}

// ---------------- layernorm + residual: one row per WAVE (1024 blocks, no LDS/barriers)
// Butterfly per 64-col group reproduces old per-wave reduce bitwise; top combine
// ((s0+s1)+s2)+s3 matches old scratch[0]+scratch[1]+scratch[2]+scratch[3].
__global__ __launch_bounds__(256) void k_ln_res(const float* __restrict__ p01,
                                                const float* __restrict__ p23,
                                                const float* __restrict__ g,
                                                const float* __restrict__ bb,
                                                float* __restrict__ h,
                                                unsigned short* __restrict__ hh,
                                                unsigned short* __restrict__ hl) {
    int t = threadIdx.x;
    int lane = t & 63, w = t >> 6;
    int r = blockIdx.x * 4 + w;
    size_t base = (size_t)r * DM;
    size_t off = (size_t)ROWS * DM;
    int c0 = lane, c1 = lane + 64, c2 = lane + 128, c3 = lane + 192;
    float v0 = p01[base + c0] + p01[base + c0 + off] + p23[base + c0] + p23[base + c0 + off];
    float v1 = p01[base + c1] + p01[base + c1 + off] + p23[base + c1] + p23[base + c1 + off];
    float v2 = p01[base + c2] + p01[base + c2 + off] + p23[base + c2] + p23[base + c2 + off];
    float v3 = p01[base + c3] + p01[base + c3 + off] + p23[base + c3] + p23[base + c3 + off];
    float s0 = v0, s1 = v1, s2 = v2, s3 = v3;
#pragma unroll
    for (int m = 32; m >= 1; m >>= 1) {
        s0 += __shfl_xor(s0, m, 64);
        s1 += __shfl_xor(s1, m, 64);
        s2 += __shfl_xor(s2, m, 64);
        s3 += __shfl_xor(s3, m, 64);
    }
    float mu = (s0 + s1 + s2 + s3) * (1.f / DM);
    float d0 = v0 - mu, d1 = v1 - mu, d2 = v2 - mu, d3 = v3 - mu;
    float q0 = d0 * d0, q1 = d1 * d1, q2 = d2 * d2, q3 = d3 * d3;
#pragma unroll
    for (int m = 32; m >= 1; m >>= 1) {
        q0 += __shfl_xor(q0, m, 64);
        q1 += __shfl_xor(q1, m, 64);
        q2 += __shfl_xor(q2, m, 64);
        q3 += __shfl_xor(q3, m, 64);
    }
    float var = (q0 + q1 + q2 + q3) * (1.f / DM);
    float rstd = 1.f / sqrtf(var + 1e-5f);
    float nv0 = h[base + c0] + d0 * rstd * g[c0] + bb[c0];
    float nv1 = h[base + c1] + d1 * rstd * g[c1] + bb[c1];
    float nv2 = h[base + c2] + d2 * rstd * g[c2] + bb[c2];
    float nv3 = h[base + c3] + d3 * rstd * g[c3] + bb[c3];
    h[base + c0] = nv0; h[base + c1] = nv1; h[base + c2] = nv2; h[base + c3] = nv3;
    unsigned short vh, vl;
    split16(nv0, vh, vl); { size_t fa = fragAddr(r, c0, 256); hh[fa] = vh; hl[fa] = vl; }
    split16(nv1, vh, vl); { size_t fa = fragAddr(r, c1, 256); hh[fa] = vh; hl[fa] = vl; }
    split16(nv2, vh, vl); { size_t fa = fragAddr(r, c2, 256); hh[fa] = vh; hl[fa] = vl; }
    split16(nv3, vh, vl); { size_t fa = fragAddr(r, c3, 256); hh[fa] = vh; hl[fa] = vl; }
}

// ---------------- mean over L (partials, deterministic) ----------------
__global__ __launch_bounds__(256) void k_meanp(const float* __restrict__ h,
                                               float* __restrict__ part) {
    int bid = blockIdx.x;
    int b = bid >> 3, g = bid & 7;
    int t = threadIdx.x;
    float s = 0.f;
    for (int k = 0; k < 128; ++k)
        s += h[(size_t)(b * LTOT + g * 128 + k) * DM + t];
    part[(size_t)bid * DM + t] = s;
}

// ---------------- head (float4 weight streams, same FMA order) ----------------
__global__ __launch_bounds__(256) void k_head(const float* __restrict__ part,
                                              const float* __restrict__ w1,
                                              const float* __restrict__ b1,
                                              const float* __restrict__ w2,
                                              const float* __restrict__ b2,
                                              float* __restrict__ out) {
    __shared__ float pl[DM], hl[DM];
    int b = blockIdx.x, t = threadIdx.x;
    float s = 0.f;
    for (int g = 0; g < 8; ++g) s += part[(size_t)(b * 8 + g) * DM + t];
    pl[t] = s * (1.f / LTOT);
    __syncthreads();
    float a = b1[t];
    const float4* w1p = (const float4*)(w1 + (size_t)t * DM);
    for (int k = 0; k < DM / 4; ++k) {
        float4 w = w1p[k];
        a = fmaf(pl[k * 4 + 0], w.x, a);
        a = fmaf(pl[k * 4 + 1], w.y, a);
        a = fmaf(pl[k * 4 + 2], w.z, a);
        a = fmaf(pl[k * 4 + 3], w.w, a);
    }
    hl[t] = fmaxf(a, 0.f);
    __syncthreads();
    if (t < NH) {
        float o = b2[t];
        const float4* w2p = (const float4*)(w2 + (size_t)t * DM);
        for (int k = 0; k < DM / 4; ++k) {
            float4 w = w2p[k];
            o = fmaf(hl[k * 4 + 0], w.x, o);
            o = fmaf(hl[k * 4 + 1], w.y, o);
            o = fmaf(hl[k * 4 + 2], w.z, o);
            o = fmaf(hl[k * 4 + 3], w.w, o);
        }
        out[b * NH + t] = o;
    }
}

extern "C" void kernel_launch(void* const* d_in, const int* in_sizes, int n_in,
                              void* d_out, int out_size, void* d_ws, size_t ws_size,
                              hipStream_t stream) {
    const float* x        = (const float*)d_in[0];
    const float* proj_w   = (const float*)d_in[1];
    const float* proj_b   = (const float*)d_in[2];
    const float* inproj_w = (const float*)d_in[3];
    const float* conv_w   = (const float*)d_in[4];
    const float* conv_b   = (const float*)d_in[5];
    const float* xproj_w  = (const float*)d_in[6];
    const float* dtproj_w = (const float*)d_in[7];
    const float* dtproj_b = (const float*)d_in[8];
    const float* A_log    = (const float*)d_in[9];
    const float* Dp       = (const float*)d_in[10];
    const float* outproj_w= (const float*)d_in[11];
    const float* ln_g     = (const float*)d_in[12];
    const float* ln_b     = (const float*)d_in[13];
    const float* head_w1  = (const float*)d_in[14];
    const float* head_b1  = (const float*)d_in[15];
    const float* head_w2  = (const float*)d_in[16];
    const float* head_b2  = (const float*)d_in[17];

    float* ws    = (float*)d_ws;
    float* h     = ws;                    // 1,048,576 f
    float* xz    = h + 1048576;           // 4,194,304 f
    float* uc    = xz + 4194304;          // 2,097,152 f
    float* dbp   = uc + 2097152;          //   786,432 f (4096*192 dbc partials)
    float* delta = dbp + 786432;          // 2,097,152 f
    float* BC    = delta + 2097152;       //   131,072 f
    float* Pbuf  = BC + 131072;           //   524,288 f
    float* hLbuf = Pbuf + 524288;         //   524,288 f
    float* p01   = hLbuf + 524288;        // 2,097,152 f (gemm_out partials 0,1)
    float* p23   = p01 + 2097152;         // 2,097,152 f (gemm_out partials 2,3)
    float* part  = p23 + 2097152;         //     8,192 f
    unsigned short* h_hi  = (unsigned short*)(part + 8192);  // 4096*256 ush (fragment order)
    unsigned short* h_lo  = h_hi + 1048576;
    unsigned short* y_hi  = h_lo + 1048576;                  // 4096*512 ush (fragment order)
    unsigned short* y_lo  = y_hi + 2097152;
    unsigned short* iw_hi = y_lo + 2097152;                  // 4*1024*256 ush (fragment order)
    unsigned short* iw_lo = iw_hi + 1048576;
    unsigned short* ow_hi = iw_lo + 1048576;                 // 4*256*512 ush (fragment order)
    unsigned short* ow_lo = ow_hi + 524288;

    k_init<<<1792, 256, 0, stream>>>(x, proj_w, proj_b, inproj_w, outproj_w,
                                     h, h_hi, h_lo, iw_hi, iw_lo, ow_hi, ow_lo);

    for (int i = 0; i < NLAY; ++i) {
        const float* cwi  = conv_w + (size_t)i * DI * 4;
        const float* cbi  = conv_b + (size_t)i * DI;
        const float* xpw  = xproj_w + (size_t)i * NXP * DI;
        const float* dtw  = dtproj_w + (size_t)i * DI * DTRN;
        const float* dtb  = dtproj_b + (size_t)i * DI;
        const float* Ali  = A_log + (size_t)i * DI * DS;
        const float* Dpi  = Dp + (size_t)i * DI;
        const float* gi   = ln_g + (size_t)i * DM;
        const float* bi   = ln_b + (size_t)i * DM;

        k_gemm_xz<<<1024, 256, 0, stream>>>(h_hi, h_lo,
                                            iw_hi + (size_t)i * 262144, iw_lo + (size_t)i * 262144, xz);
        k_dbcp<<<512, 256, 0, stream>>>(xz, cwi, cbi, xpw, uc, dbp);
        k_dbcr<<<ROWS / 8, 256, 0, stream>>>(dbp, dtw, dtb, delta, BC);
        k_scanA<<<BB * 32 * NC, 256, 0, stream>>>(delta, uc, BC, Ali, Pbuf, hLbuf);
        k_scanC<<<BB * 32 * NC, 256, 0, stream>>>(delta, uc, BC, Ali, Pbuf, hLbuf, Dpi, xz, y_hi, y_lo);
        k_gemm_out<<<1024, 256, 0, stream>>>(y_hi, y_lo,
                                             ow_hi + (size_t)i * 131072, ow_lo + (size_t)i * 131072,
                                             p01, p23);
        k_ln_res<<<ROWS / 4, 256, 0, stream>>>(p01, p23, gi, bi, h, h_hi, h_lo);
    }

    k_meanp<<<32, 256, 0, stream>>>(h, part);
    k_head<<<BB, 256, 0, stream>>>(part, head_w1, head_b1, head_w2, head_b2, (float*)d_out);
}

// Round 16
// 435.668 us; speedup vs baseline: 1.0411x; 1.0103x over previous
//
#include <hip/hip_runtime.h>
#include <hip/hip_fp16.h>
#include <math.h>

// Problem dims
#define LTOT 1024
#define BB   4
#define F_IN 32
#define DM   256
#define DI   512
#define DS   16
#define DTRN 16
#define NXP  48         // DTR + 2*DS
#define NLAY 4
#define NH   4
#define NC   16         // scan chunks
#define CLEN 64         // L / NC
#define ROWS (BB*LTOT)  // 4096

typedef _Float16 half8 __attribute__((ext_vector_type(8)));
typedef float f32x16 __attribute__((ext_vector_type(16)));

__device__ __forceinline__ float siluf_(float x) { return x / (1.0f + expf(-x)); }
__device__ __forceinline__ float softplusf_(float x) {
    if (x > 20.f) return x;
    if (x < -20.f) return expf(x);
    return log1pf(expf(x));
}

// fp16 2-piece split: x ~= hi + lo with ~22-bit combined mantissa
__device__ __forceinline__ void split16(float x, unsigned short& hi, unsigned short& lo) {
    __half h = __float2half(x);
    hi = *(unsigned short*)&h;
    float r = x - __half2float(h);
    __half l = __float2half(r);
    lo = *(unsigned short*)&l;
}

// MFMA fragment-order address for element (r, k) of a matrix with k-dim Kd.
__device__ __forceinline__ size_t fragAddr(int r, int k, int Kd) {
    return ((size_t)((r >> 5) * (Kd >> 4) + (k >> 4)) << 9)
         + (size_t)(((((k >> 3) & 1) << 5) + (r & 31)) * 8 + (k & 7));
}

// ---------------- init: fused weight-split->fragment (blocks 0..1535) + proj (1536..1791) ----
__global__ __launch_bounds__(256) void k_init(const float* __restrict__ x,
                                              const float* __restrict__ pw,
                                              const float* __restrict__ pb,
                                              const float* __restrict__ inw,
                                              const float* __restrict__ outw,
                                              float* __restrict__ h,
                                              unsigned short* __restrict__ hh,
                                              unsigned short* __restrict__ hl,
                                              unsigned short* __restrict__ iwh,
                                              unsigned short* __restrict__ iwl,
                                              unsigned short* __restrict__ owh,
                                              unsigned short* __restrict__ owl) {
    __shared__ float wl[DM][33];
    __shared__ float xl[16][32];
    int bid = blockIdx.x, t = threadIdx.x;
    if (bid < 1536) {   // ---- weight split into fragment order ----
        int q = bid * 256 + t;
        ushort4 h4, l4;
        if (q < 262144) {                          // inw: 4 layers x 1024 rows x K=256
            float4 v = ((const float4*)inw)[q];
            split16(v.x, h4.x, l4.x); split16(v.y, h4.y, l4.y);
            split16(v.z, h4.z, l4.z); split16(v.w, h4.w, l4.w);
            int row = q >> 6, k0 = (q & 63) * 4;
            int lay = row >> 10, rIn = row & 1023;
            size_t fa = (size_t)lay * 262144 + fragAddr(rIn, k0, 256);
            *(ushort4*)(iwh + fa) = h4;
            *(ushort4*)(iwl + fa) = l4;
        } else {
            int rq = q - 262144;                   // outw: 4 layers x 256 rows x K=512
            float4 v = ((const float4*)outw)[rq];
            split16(v.x, h4.x, l4.x); split16(v.y, h4.y, l4.y);
            split16(v.z, h4.z, l4.z); split16(v.w, h4.w, l4.w);
            int row = rq >> 7, k0 = (rq & 127) * 4;
            int lay = row >> 8, rIn = row & 255;
            size_t fa = (size_t)lay * 131072 + fragAddr(rIn, k0, 512);
            *(ushort4*)(owh + fa) = h4;
            *(ushort4*)(owl + fa) = l4;
        }
        return;
    }
    // ---- proj: h = x @ proj_w.T + proj_b (+ fragment-order fp16 emit) ----
    int r0 = (bid - 1536) * 16;
    for (int i = t; i < DM * 32 / 4; i += 256) {
        float4 v = ((const float4*)pw)[i];
        int c = i / 8, k = (i % 8) * 4;
        wl[c][k] = v.x; wl[c][k + 1] = v.y; wl[c][k + 2] = v.z; wl[c][k + 3] = v.w;
    }
    for (int i = t; i < 16 * 32 / 4; i += 256) {
        float4 v = ((const float4*)(x + (size_t)r0 * F_IN))[i];
        int r = i / 8, k = (i % 8) * 4;
        xl[r][k] = v.x; xl[r][k + 1] = v.y; xl[r][k + 2] = v.z; xl[r][k + 3] = v.w;
    }
    __syncthreads();
    int c = t;
    float bias = pb[c];
    float acc[16];
#pragma unroll
    for (int r = 0; r < 16; ++r) acc[r] = bias;
    for (int k = 0; k < 32; ++k) {
        float w = wl[c][k];
#pragma unroll
        for (int r = 0; r < 16; ++r) acc[r] = fmaf(xl[r][k], w, acc[r]);
    }
#pragma unroll
    for (int r = 0; r < 16; ++r) {
        int rr = r0 + r;
        h[(size_t)rr * DM + c] = acc[r];
        unsigned short vh, vl; split16(acc[r], vh, vl);
        size_t fa = fragAddr(rr, c, 256);
        hh[fa] = vh; hl[fa] = vl;
    }
}

// ---------------- gemm_xz (MFMA, fragment-streamed, depth-2, 1024 blocks x 64x64) -----
__global__ __launch_bounds__(256) void k_gemm_xz(const unsigned short* __restrict__ Ahp,
                                                 const unsigned short* __restrict__ Alp,
                                                 const unsigned short* __restrict__ Bhp,
                                                 const unsigned short* __restrict__ Blp,
                                                 float* __restrict__ C) {
    int t = threadIdx.x;
    int bx = blockIdx.x & 15;     // colblock of 64
    int by = blockIdx.x >> 4;     // rowblock of 64
    int lane = t & 63, wid = t >> 6;
    int fr = lane & 31, fg = lane >> 5;
    int wr = wid >> 1, wc = wid & 1;
    int rt = by * 2 + wr;
    int ct = bx * 2 + wc;
    const half8* pAh = (const half8*)Ahp + (size_t)rt * 1024 + lane;
    const half8* pAl = (const half8*)Alp + (size_t)rt * 1024 + lane;
    const half8* pBh = (const half8*)Bhp + (size_t)ct * 1024 + lane;
    const half8* pBl = (const half8*)Blp + (size_t)ct * 1024 + lane;
    f32x16 acc = {};
    half8 ah0 = pAh[0],  al0 = pAl[0],  bh0 = pBh[0],  bl0 = pBl[0];
    half8 ah1 = pAh[64], al1 = pAl[64], bh1 = pBh[64], bl1 = pBl[64];
#pragma unroll
    for (int kt = 0; kt < 16; kt += 2) {
        half8 nah, nal, nbh, nbl;
        if (kt + 2 < 16) {
            int o = (kt + 2) * 64;
            nah = pAh[o]; nal = pAl[o]; nbh = pBh[o]; nbl = pBl[o];
        }
        acc = __builtin_amdgcn_mfma_f32_32x32x16_f16(ah0, bh0, acc, 0, 0, 0);
        acc = __builtin_amdgcn_mfma_f32_32x32x16_f16(ah0, bl0, acc, 0, 0, 0);
        acc = __builtin_amdgcn_mfma_f32_32x32x16_f16(al0, bh0, acc, 0, 0, 0);
        if (kt + 2 < 16) { ah0 = nah; al0 = nal; bh0 = nbh; bl0 = nbl; }
        half8 mah, mal, mbh, mbl;
        if (kt + 3 < 16) {
            int o = (kt + 3) * 64;
            mah = pAh[o]; mal = pAl[o]; mbh = pBh[o]; mbl = pBl[o];
        }
        acc = __builtin_amdgcn_mfma_f32_32x32x16_f16(ah1, bh1, acc, 0, 0, 0);
        acc = __builtin_amdgcn_mfma_f32_32x32x16_f16(ah1, bl1, acc, 0, 0, 0);
        acc = __builtin_amdgcn_mfma_f32_32x32x16_f16(al1, bh1, acc, 0, 0, 0);
        if (kt + 3 < 16) { ah1 = mah; al1 = mal; bh1 = mbh; bl1 = mbl; }
    }
    float* Cp = C + (size_t)(by * 64 + wr * 32) * 1024 + bx * 64 + wc * 32;
#pragma unroll
    for (int reg = 0; reg < 16; ++reg) {
        int row = (reg & 3) + 8 * (reg >> 2) + 4 * fg;
        Cp[(size_t)row * 1024 + fr] = acc[reg];
    }
}

// ---------------- dbc partial GEMM (split-K by 4) with fused causal conv+silu --------
// R12-proven form: 512 blocks x 32 rows, early weight-issue.
__global__ __launch_bounds__(256) void k_dbcp(const float* __restrict__ xz,
                                              const float* __restrict__ cw,
                                              const float* __restrict__ cb,
                                              const float* __restrict__ xpw,
                                              float* __restrict__ uc,
                                              float* __restrict__ dbp) {
    __shared__ float us[32][132];
    __shared__ float wsd[48][132];
    int t = threadIdx.x;
    int kp = blockIdx.x & 3;
    int r0 = (blockIdx.x >> 2) * 32;
    int k0 = kp * 128;
    float4* us4 = (float4*)us;
    float4* ws4 = (float4*)wsd;
    float4 wreg0, wreg1, wreg2, wreg3, wreg4, wreg5;
    {
        int i0 = t;            wreg0 = *(const float4*)(xpw + (size_t)(i0 >> 5) * DI + k0 + (i0 & 31) * 4);
        int i1 = t + 256;      wreg1 = *(const float4*)(xpw + (size_t)(i1 >> 5) * DI + k0 + (i1 & 31) * 4);
        int i2 = t + 512;      wreg2 = *(const float4*)(xpw + (size_t)(i2 >> 5) * DI + k0 + (i2 & 31) * 4);
        int i3 = t + 768;      wreg3 = *(const float4*)(xpw + (size_t)(i3 >> 5) * DI + k0 + (i3 & 31) * 4);
        int i4 = t + 1024;     wreg4 = *(const float4*)(xpw + (size_t)(i4 >> 5) * DI + k0 + (i4 & 31) * 4);
        int i5 = t + 1280;     wreg5 = *(const float4*)(xpw + (size_t)(i5 >> 5) * DI + k0 + (i5 & 31) * 4);
    }
#pragma unroll
    for (int j = 0; j < 4; ++j) {
        int i = t + j * 256;
        int r = i >> 5, kq = i & 31;
        int rr = r0 + r, d = k0 + kq * 4;
        int tt = rr & (LTOT - 1);
        float4 acc = make_float4(cb[d], cb[d + 1], cb[d + 2], cb[d + 3]);
#pragma unroll
        for (int k = 0; k < 4; ++k) {
            int ts = tt - 3 + k;
            if (ts < 0) continue;
            float4 u = *(const float4*)(xz + (size_t)(rr - 3 + k) * 1024 + d);
            acc.x = fmaf(u.x, cw[(d + 0) * 4 + k], acc.x);
            acc.y = fmaf(u.y, cw[(d + 1) * 4 + k], acc.y);
            acc.z = fmaf(u.z, cw[(d + 2) * 4 + k], acc.z);
            acc.w = fmaf(u.w, cw[(d + 3) * 4 + k], acc.w);
        }
        acc.x = siluf_(acc.x); acc.y = siluf_(acc.y); acc.z = siluf_(acc.z); acc.w = siluf_(acc.w);
        us4[r * 33 + kq] = acc;
        *(float4*)(uc + (size_t)rr * DI + d) = acc;
    }
    {
        int i0 = t;        ws4[(i0 >> 5) * 33 + (i0 & 31)] = wreg0;
        int i1 = t + 256;  ws4[(i1 >> 5) * 33 + (i1 & 31)] = wreg1;
        int i2 = t + 512;  ws4[(i2 >> 5) * 33 + (i2 & 31)] = wreg2;
        int i3 = t + 768;  ws4[(i3 >> 5) * 33 + (i3 & 31)] = wreg3;
        int i4 = t + 1024; ws4[(i4 >> 5) * 33 + (i4 & 31)] = wreg4;
        int i5 = t + 1280; ws4[(i5 >> 5) * 33 + (i5 & 31)] = wreg5;
    }
    __syncthreads();
    int tx = t & 15, ty = t >> 4;
    const float4* ua = us4 + (ty * 2) * 33;
    const float4* ub = ua + 33;
    const float4* w0p = ws4 + (tx * 3) * 33;
    const float4* w1p = w0p + 33;
    const float4* w2p = w0p + 66;
    float acc[2][3] = {};
#pragma unroll 4
    for (int kq = 0; kq < 32; ++kq) {
        float4 u0 = ua[kq], u1 = ub[kq];
        float4 w0 = w0p[kq], w1 = w1p[kq], w2 = w2p[kq];
        acc[0][0] = fmaf(u0.x, w0.x, acc[0][0]); acc[0][0] = fmaf(u0.y, w0.y, acc[0][0]);
        acc[0][0] = fmaf(u0.z, w0.z, acc[0][0]); acc[0][0] = fmaf(u0.w, w0.w, acc[0][0]);
        acc[0][1] = fmaf(u0.x, w1.x, acc[0][1]); acc[0][1] = fmaf(u0.y, w1.y, acc[0][1]);
        acc[0][1] = fmaf(u0.z, w1.z, acc[0][1]); acc[0][1] = fmaf(u0.w, w1.w, acc[0][1]);
        acc[0][2] = fmaf(u0.x, w2.x, acc[0][2]); acc[0][2] = fmaf(u0.y, w2.y, acc[0][2]);
        acc[0][2] = fmaf(u0.z, w2.z, acc[0][2]); acc[0][2] = fmaf(u0.w, w2.w, acc[0][2]);
        acc[1][0] = fmaf(u1.x, w0.x, acc[1][0]); acc[1][0] = fmaf(u1.y, w0.y, acc[1][0]);
        acc[1][0] = fmaf(u1.z, w0.z, acc[1][0]); acc[1][0] = fmaf(u1.w, w0.w, acc[1][0]);
        acc[1][1] = fmaf(u1.x, w1.x, acc[1][1]); acc[1][1] = fmaf(u1.y, w1.y, acc[1][1]);
        acc[1][1] = fmaf(u1.z, w1.z, acc[1][1]); acc[1][1] = fmaf(u1.w, w1.w, acc[1][1]);
        acc[1][2] = fmaf(u1.x, w2.x, acc[1][2]); acc[1][2] = fmaf(u1.y, w2.y, acc[1][2]);
        acc[1][2] = fmaf(u1.z, w2.z, acc[1][2]); acc[1][2] = fmaf(u1.w, w2.w, acc[1][2]);
    }
    float* outp = dbp + (size_t)(r0 + ty * 2) * 192 + kp * 48 + tx * 3;
    outp[0] = acc[0][0]; outp[1] = acc[0][1]; outp[2] = acc[0][2];
    outp[192] = acc[1][0]; outp[193] = acc[1][1]; outp[194] = acc[1][2];
}

// ---------------- dbc reduce + BC extract + delta (1024 blocks x 4 rows) ----------------
__global__ __launch_bounds__(256) void k_dbcr(const float* __restrict__ dbp,
                                              const float* __restrict__ dtw,
                                              const float* __restrict__ dtb,
                                              float* __restrict__ delta,
                                              float* __restrict__ BC) {
    __shared__ float dbl[4][NXP];
    int t = threadIdx.x;
    int r0 = blockIdx.x * 4;
    if (t < 64) {
        int r = t >> 4, c3 = (t & 15) * 3;
        const float* pp = dbp + (size_t)(r0 + r) * 192 + c3;
#pragma unroll
        for (int j = 0; j < 3; ++j) {
            float s = pp[j] + pp[48 + j] + pp[96 + j] + pp[144 + j];
            dbl[r][c3 + j] = s;
            int cj = c3 + j;
            if (cj >= 16) BC[(size_t)(r0 + r) * 32 + (cj - 16)] = s;
        }
    }
    __syncthreads();
    {
        int c0 = t * 2;
        float wd0[16], wd1[16];
        const float4* q0 = (const float4*)(dtw + (size_t)c0 * 16);
        const float4* q1 = (const float4*)(dtw + (size_t)(c0 + 1) * 16);
#pragma unroll
        for (int j = 0; j < 4; ++j) { *(float4*)&wd0[j * 4] = q0[j]; *(float4*)&wd1[j * 4] = q1[j]; }
        float bb0 = dtb[c0], bb1 = dtb[c0 + 1];
        for (int r = 0; r < 4; ++r) {
            float s0 = bb0, s1 = bb1;
#pragma unroll
            for (int k = 0; k < 16; ++k) {
                float dv = dbl[r][k];
                s0 = fmaf(dv, wd0[k], s0);
                s1 = fmaf(dv, wd1[k], s1);
            }
            *(float2*)(delta + (size_t)(r0 + r) * DI + c0) =
                make_float2(softplusf_(s0), softplusf_(s1));
        }
    }
}

// ---------------- scan pass A (chunk 15 skipped: its P/hL are never consumed) ---------
__global__ __launch_bounds__(256) void k_scanA(const float* __restrict__ delta,
                                               const float* __restrict__ uc,
                                               const float* __restrict__ BC,
                                               const float* __restrict__ A_log,
                                               float* __restrict__ P,
                                               float* __restrict__ hL) {
    __shared__ float2 du2[CLEN][16];
    __shared__ float  Bl[CLEN][16];
    int bid = blockIdx.x;
    int c = bid & 15, dblk = (bid >> 4) & 31, b = bid >> 9;
    if (c == 15) return;   // chunk 15 outputs unused by scanC (reads cc < c <= 14)
    int d0 = dblk * 16, t0 = c * CLEN;
    int t = threadIdx.x;
    {
        int row = t >> 2, hf = (t & 3) * 4;
        size_t rbase = (size_t)(b * LTOT + t0 + row);
        float4 dv = *(const float4*)(delta + rbase * DI + d0 + hf);
        float4 uv = *(const float4*)(uc + rbase * DI + d0 + hf);
        float4* dst = (float4*)&du2[row][hf];
        dst[0] = make_float4(dv.x, uv.x, dv.y, uv.y);
        dst[1] = make_float4(dv.z, uv.z, dv.w, uv.w);
        *(float4*)&Bl[row][hf] = *(const float4*)(BC + rbase * 32 + hf);
    }
    __syncthreads();
    int n = t & 15, dn = t >> 4;
    float Ac = -expf(A_log[(size_t)(d0 + dn) * DS + n]);
    float h = 0.f, Pp = 1.f;
#pragma unroll 8
    for (int k = 0; k < CLEN; ++k) {
        float2 du = du2[k][dn];
        float Bv = Bl[k][n];
        float a = expf(du.x * Ac);
        Pp *= a;
        h = fmaf(a, h, du.x * du.y * Bv);
    }
    size_t idx = ((size_t)(b * NC + c)) * (DI * DS) + (size_t)d0 * DS + t;
    P[idx] = Pp;
    hL[idx] = h;
}

// ---------------- scan pass C (ytmp LDS reduce; Hin loads prefetched after barrier) ---
__global__ __launch_bounds__(256) void k_scanC(const float* __restrict__ delta,
                                               const float* __restrict__ uc,
                                               const float* __restrict__ BC,
                                               const float* __restrict__ A_log,
                                               const float* __restrict__ P,
                                               const float* __restrict__ hL,
                                               const float* __restrict__ Dp,
                                               const float* __restrict__ xz,
                                               unsigned short* __restrict__ yh,
                                               unsigned short* __restrict__ yl) {
    __shared__ float2 du2[CLEN][16];
    __shared__ float2 bc2[CLEN][16];
    __shared__ float  zs[CLEN][16];
    __shared__ float  ytmp[16][16][20];
    int bid = blockIdx.x;
    int c = bid & 15, dblk = (bid >> 4) & 31, b = bid >> 9;
    int d0 = dblk * 16, t0 = c * CLEN;
    int t = threadIdx.x;
    {
        int row = t >> 2, hf = (t & 3) * 4;
        size_t rbase = (size_t)(b * LTOT + t0 + row);
        float4 dv = *(const float4*)(delta + rbase * DI + d0 + hf);
        float4 uv = *(const float4*)(uc + rbase * DI + d0 + hf);
        float4* dst = (float4*)&du2[row][hf];
        dst[0] = make_float4(dv.x, uv.x, dv.y, uv.y);
        dst[1] = make_float4(dv.z, uv.z, dv.w, uv.w);
        float4 bv = *(const float4*)(BC + rbase * 32 + hf);
        float4 cv = *(const float4*)(BC + rbase * 32 + 16 + hf);
        float4* bdst = (float4*)&bc2[row][hf];
        bdst[0] = make_float4(bv.x, cv.x, bv.y, cv.y);
        bdst[1] = make_float4(bv.z, cv.z, bv.w, cv.w);
        *(float4*)&zs[row][hf] = *(const float4*)(xz + rbase * 1024 + 512 + d0 + hf);
    }
    __syncthreads();
    int n = t & 15, dn = t >> 4;
    float Ac = -expf(A_log[(size_t)(d0 + dn) * DS + n]);
    // Hin: fully-unrolled guarded prefetch (independent loads), then exact-order chain
    float Hin = 0.f;
    {
        float pv[15], hv[15];
#pragma unroll
        for (int cc = 0; cc < 15; ++cc) {
            pv[cc] = 0.f; hv[cc] = 0.f;
            if (cc < c) {
                size_t idx = ((size_t)(b * NC + cc)) * (DI * DS) + (size_t)d0 * DS + t;
                pv[cc] = P[idx];
                hv[cc] = hL[idx];
            }
        }
#pragma unroll
        for (int cc = 0; cc < 15; ++cc) {
            if (cc < c) Hin = fmaf(pv[cc], Hin, hv[cc]);
        }
    }
    float h = Hin;
    int rdn = t & 15, rk = t >> 4;
    float DpV = Dp[d0 + rdn];
    for (int s = 0; s < CLEN / 16; ++s) {
#pragma unroll
        for (int kk = 0; kk < 16; ++kk) {
            int k = s * 16 + kk;
            float2 du = du2[k][dn];
            float2 bc = bc2[k][n];
            float a = expf(du.x * Ac);
            h = fmaf(a, h, du.x * du.y * bc.x);
            ytmp[kk][dn][n] = h * bc.y;
        }
        __syncthreads();
        {
            const float* rowp = &ytmp[rk][rdn][0];
            float4 v0 = *(const float4*)(rowp + 0);
            float4 v1 = *(const float4*)(rowp + 4);
            float4 v2 = *(const float4*)(rowp + 8);
            float4 v3 = *(const float4*)(rowp + 12);
            float y = ((v0.x + v0.y) + (v0.z + v0.w)) + ((v1.x + v1.y) + (v1.z + v1.w))
                    + ((v2.x + v2.y) + (v2.z + v2.w)) + ((v3.x + v3.y) + (v3.z + v3.w));
            float uu = du2[s * 16 + rk][rdn].y;
            float z = zs[s * 16 + rk][rdn];
            size_t rb2 = (size_t)(b * LTOT + t0 + s * 16 + rk);
            float val = fmaf(uu, DpV, y) * siluf_(z);
            unsigned short vh, vl; split16(val, vh, vl);
            size_t fa = fragAddr((int)rb2, d0 + rdn, 512);
            yh[fa] = vh; yl[fa] = vl;
        }
        __syncthreads();
    }
}

// ---------------- gemm_out (MFMA, fragment-streamed, depth-2, 1024 blocks x 32x128) ----
__global__ __launch_bounds__(256) void k_gemm_out(const unsigned short* __restrict__ Ahp,
                                                  const unsigned short* __restrict__ Alp,
                                                  const unsigned short* __restrict__ Bhp,
                                                  const unsigned short* __restrict__ Blp,
                                                  float* __restrict__ p01,
                                                  float* __restrict__ p23) {
    int t = threadIdx.x;
    int bx = blockIdx.x & 1;               // 128-col block
    int by = (blockIdx.x >> 1) & 127;      // 32-row block
    int kp = blockIdx.x >> 8;              // K=128 slice
    int lane = t & 63, wid = t >> 6;
    int fr = lane & 31, fg = lane >> 5;
    int rt = by;
    int ct = bx * 4 + wid;                 // 4 coltiles of 32, one per wave
    const half8* pAh = (const half8*)Ahp + (size_t)rt * 2048 + (size_t)kp * 512 + lane;
    const half8* pAl = (const half8*)Alp + (size_t)rt * 2048 + (size_t)kp * 512 + lane;
    const half8* pBh = (const half8*)Bhp + (size_t)ct * 2048 + (size_t)kp * 512 + lane;
    const half8* pBl = (const half8*)Blp + (size_t)ct * 2048 + (size_t)kp * 512 + lane;
    f32x16 acc = {};
    half8 ah0 = pAh[0],  al0 = pAl[0],  bh0 = pBh[0],  bl0 = pBl[0];
    half8 ah1 = pAh[64], al1 = pAl[64], bh1 = pBh[64], bl1 = pBl[64];
#pragma unroll
    for (int kt = 0; kt < 8; kt += 2) {
        half8 nah, nal, nbh, nbl;
        if (kt + 2 < 8) {
            int o = (kt + 2) * 64;
            nah = pAh[o]; nal = pAl[o]; nbh = pBh[o]; nbl = pBl[o];
        }
        acc = __builtin_amdgcn_mfma_f32_32x32x16_f16(ah0, bh0, acc, 0, 0, 0);
        acc = __builtin_amdgcn_mfma_f32_32x32x16_f16(ah0, bl0, acc, 0, 0, 0);
        acc = __builtin_amdgcn_mfma_f32_32x32x16_f16(al0, bh0, acc, 0, 0, 0);
        if (kt + 2 < 8) { ah0 = nah; al0 = nal; bh0 = nbh; bl0 = nbl; }
        half8 mah, mal, mbh, mbl;
        if (kt + 3 < 8) {
            int o = (kt + 3) * 64;
            mah = pAh[o]; mal = pAl[o]; mbh = pBh[o]; mbl = pBl[o];
        }
        acc = __builtin_amdgcn_mfma_f32_32x32x16_f16(ah1, bh1, acc, 0, 0, 0);
        acc = __builtin_amdgcn_mfma_f32_32x32x16_f16(ah1, bl1, acc, 0, 0, 0);
        acc = __builtin_amdgcn_mfma_f32_32x32x16_f16(al1, bh1, acc, 0, 0, 0);
        if (kt + 3 < 8) { ah1 = mah; al1 = mal; bh1 = mbh; bl1 = mbl; }
    }
    float* pbase = (kp < 2 ? p01 : p23) + (size_t)(kp & 1) * (ROWS * DM);
    float* Cp = pbase + (size_t)(by * 32) * DM + bx * 128 + wid * 32;
#pragma unroll
    for (int reg = 0; reg < 16; ++reg) {
        int row = (reg & 3) + 8 * (reg >> 2) + 4 * fg;
        Cp[(size_t)row * DM + fr] = acc[reg];
    }
}

// ---------------- layernorm + residual: one row per WAVE (1024 blocks, no LDS/barriers)
__global__ __launch_bounds__(256) void k_ln_res(const float* __restrict__ p01,
                                                const float* __restrict__ p23,
                                                const float* __restrict__ g,
                                                const float* __restrict__ bb,
                                                float* __restrict__ h,
                                                unsigned short* __restrict__ hh,
                                                unsigned short* __restrict__ hl) {
    int t = threadIdx.x;
    int lane = t & 63, w = t >> 6;
    int r = blockIdx.x * 4 + w;
    size_t base = (size_t)r * DM;
    size_t off = (size_t)ROWS * DM;
    int c0 = lane, c1 = lane + 64, c2 = lane + 128, c3 = lane + 192;
    float v0 = p01[base + c0] + p01[base + c0 + off] + p23[base + c0] + p23[base + c0 + off];
    float v1 = p01[base + c1] + p01[base + c1 + off] + p23[base + c1] + p23[base + c1 + off];
    float v2 = p01[base + c2] + p01[base + c2 + off] + p23[base + c2] + p23[base + c2 + off];
    float v3 = p01[base + c3] + p01[base + c3 + off] + p23[base + c3] + p23[base + c3 + off];
    float s0 = v0, s1 = v1, s2 = v2, s3 = v3;
#pragma unroll
    for (int m = 32; m >= 1; m >>= 1) {
        s0 += __shfl_xor(s0, m, 64);
        s1 += __shfl_xor(s1, m, 64);
        s2 += __shfl_xor(s2, m, 64);
        s3 += __shfl_xor(s3, m, 64);
    }
    float mu = (s0 + s1 + s2 + s3) * (1.f / DM);
    float d0 = v0 - mu, d1 = v1 - mu, d2 = v2 - mu, d3 = v3 - mu;
    float q0 = d0 * d0, q1 = d1 * d1, q2 = d2 * d2, q3 = d3 * d3;
#pragma unroll
    for (int m = 32; m >= 1; m >>= 1) {
        q0 += __shfl_xor(q0, m, 64);
        q1 += __shfl_xor(q1, m, 64);
        q2 += __shfl_xor(q2, m, 64);
        q3 += __shfl_xor(q3, m, 64);
    }
    float var = (q0 + q1 + q2 + q3) * (1.f / DM);
    float rstd = 1.f / sqrtf(var + 1e-5f);
    float nv0 = h[base + c0] + d0 * rstd * g[c0] + bb[c0];
    float nv1 = h[base + c1] + d1 * rstd * g[c1] + bb[c1];
    float nv2 = h[base + c2] + d2 * rstd * g[c2] + bb[c2];
    float nv3 = h[base + c3] + d3 * rstd * g[c3] + bb[c3];
    h[base + c0] = nv0; h[base + c1] = nv1; h[base + c2] = nv2; h[base + c3] = nv3;
    unsigned short vh, vl;
    split16(nv0, vh, vl); { size_t fa = fragAddr(r, c0, 256); hh[fa] = vh; hl[fa] = vl; }
    split16(nv1, vh, vl); { size_t fa = fragAddr(r, c1, 256); hh[fa] = vh; hl[fa] = vl; }
    split16(nv2, vh, vl); { size_t fa = fragAddr(r, c2, 256); hh[fa] = vh; hl[fa] = vl; }
    split16(nv3, vh, vl); { size_t fa = fragAddr(r, c3, 256); hh[fa] = vh; hl[fa] = vl; }
}

// ---------------- mean over L (partials; 8-deep ordered load batching) ----------------
__global__ __launch_bounds__(256) void k_meanp(const float* __restrict__ h,
                                               float* __restrict__ part) {
    int bid = blockIdx.x;
    int b = bid >> 3, g = bid & 7;
    int t = threadIdx.x;
    const float* hp = h + (size_t)(b * LTOT + g * 128) * DM + t;
    float s = 0.f;
    for (int kb = 0; kb < 128; kb += 8) {
        float v0 = hp[(size_t)(kb + 0) * DM];
        float v1 = hp[(size_t)(kb + 1) * DM];
        float v2 = hp[(size_t)(kb + 2) * DM];
        float v3 = hp[(size_t)(kb + 3) * DM];
        float v4 = hp[(size_t)(kb + 4) * DM];
        float v5 = hp[(size_t)(kb + 5) * DM];
        float v6 = hp[(size_t)(kb + 6) * DM];
        float v7 = hp[(size_t)(kb + 7) * DM];
        s = s + v0; s = s + v1; s = s + v2; s = s + v3;
        s = s + v4; s = s + v5; s = s + v6; s = s + v7;
    }
    part[(size_t)bid * DM + t] = s;
}

// ---------------- head (float4 weight streams, same FMA order) ----------------
__global__ __launch_bounds__(256) void k_head(const float* __restrict__ part,
                                              const float* __restrict__ w1,
                                              const float* __restrict__ b1,
                                              const float* __restrict__ w2,
                                              const float* __restrict__ b2,
                                              float* __restrict__ out) {
    __shared__ float pl[DM], hl[DM];
    int b = blockIdx.x, t = threadIdx.x;
    float s = 0.f;
    for (int g = 0; g < 8; ++g) s += part[(size_t)(b * 8 + g) * DM + t];
    pl[t] = s * (1.f / LTOT);
    __syncthreads();
    float a = b1[t];
    const float4* w1p = (const float4*)(w1 + (size_t)t * DM);
    for (int k = 0; k < DM / 4; ++k) {
        float4 w = w1p[k];
        a = fmaf(pl[k * 4 + 0], w.x, a);
        a = fmaf(pl[k * 4 + 1], w.y, a);
        a = fmaf(pl[k * 4 + 2], w.z, a);
        a = fmaf(pl[k * 4 + 3], w.w, a);
    }
    hl[t] = fmaxf(a, 0.f);
    __syncthreads();
    if (t < NH) {
        float o = b2[t];
        const float4* w2p = (const float4*)(w2 + (size_t)t * DM);
        for (int k = 0; k < DM / 4; ++k) {
            float4 w = w2p[k];
            o = fmaf(hl[k * 4 + 0], w.x, o);
            o = fmaf(hl[k * 4 + 1], w.y, o);
            o = fmaf(hl[k * 4 + 2], w.z, o);
            o = fmaf(hl[k * 4 + 3], w.w, o);
        }
        out[b * NH + t] = o;
    }
}

extern "C" void kernel_launch(void* const* d_in, const int* in_sizes, int n_in,
                              void* d_out, int out_size, void* d_ws, size_t ws_size,
                              hipStream_t stream) {
    const float* x        = (const float*)d_in[0];
    const float* proj_w   = (const float*)d_in[1];
    const float* proj_b   = (const float*)d_in[2];
    const float* inproj_w = (const float*)d_in[3];
    const float* conv_w   = (const float*)d_in[4];
    const float* conv_b   = (const float*)d_in[5];
    const float* xproj_w  = (const float*)d_in[6];
    const float* dtproj_w = (const float*)d_in[7];
    const float* dtproj_b = (const float*)d_in[8];
    const float* A_log    = (const float*)d_in[9];
    const float* Dp       = (const float*)d_in[10];
    const float* outproj_w= (const float*)d_in[11];
    const float* ln_g     = (const float*)d_in[12];
    const float* ln_b     = (const float*)d_in[13];
    const float* head_w1  = (const float*)d_in[14];
    const float* head_b1  = (const float*)d_in[15];
    const float* head_w2  = (const float*)d_in[16];
    const float* head_b2  = (const float*)d_in[17];

    float* ws    = (float*)d_ws;
    float* h     = ws;                    // 1,048,576 f
    float* xz    = h + 1048576;           // 4,194,304 f
    float* uc    = xz + 4194304;          // 2,097,152 f
    float* dbp   = uc + 2097152;          //   786,432 f (4096*192 dbc partials)
    float* delta = dbp + 786432;          // 2,097,152 f
    float* BC    = delta + 2097152;       //   131,072 f
    float* Pbuf  = BC + 131072;           //   524,288 f
    float* hLbuf = Pbuf + 524288;         //   524,288 f
    float* p01   = hLbuf + 524288;        // 2,097,152 f (gemm_out partials 0,1)
    float* p23   = p01 + 2097152;         // 2,097,152 f (gemm_out partials 2,3)
    float* part  = p23 + 2097152;         //     8,192 f
    unsigned short* h_hi  = (unsigned short*)(part + 8192);  // 4096*256 ush (fragment order)
    unsigned short* h_lo  = h_hi + 1048576;
    unsigned short* y_hi  = h_lo + 1048576;                  // 4096*512 ush (fragment order)
    unsigned short* y_lo  = y_hi + 2097152;
    unsigned short* iw_hi = y_lo + 2097152;                  // 4*1024*256 ush (fragment order)
    unsigned short* iw_lo = iw_hi + 1048576;
    unsigned short* ow_hi = iw_lo + 1048576;                 // 4*256*512 ush (fragment order)
    unsigned short* ow_lo = ow_hi + 524288;

    k_init<<<1792, 256, 0, stream>>>(x, proj_w, proj_b, inproj_w, outproj_w,
                                     h, h_hi, h_lo, iw_hi, iw_lo, ow_hi, ow_lo);

    for (int i = 0; i < NLAY; ++i) {
        const float* cwi  = conv_w + (size_t)i * DI * 4;
        const float* cbi  = conv_b + (size_t)i * DI;
        const float* xpw  = xproj_w + (size_t)i * NXP * DI;
        const float* dtw  = dtproj_w + (size_t)i * DI * DTRN;
        const float* dtb  = dtproj_b + (size_t)i * DI;
        const float* Ali  = A_log + (size_t)i * DI * DS;
        const float* Dpi  = Dp + (size_t)i * DI;
        const float* gi   = ln_g + (size_t)i * DM;
        const float* bi   = ln_b + (size_t)i * DM;

        k_gemm_xz<<<1024, 256, 0, stream>>>(h_hi, h_lo,
                                            iw_hi + (size_t)i * 262144, iw_lo + (size_t)i * 262144, xz);
        k_dbcp<<<512, 256, 0, stream>>>(xz, cwi, cbi, xpw, uc, dbp);
        k_dbcr<<<ROWS / 4, 256, 0, stream>>>(dbp, dtw, dtb, delta, BC);
        k_scanA<<<BB * 32 * NC, 256, 0, stream>>>(delta, uc, BC, Ali, Pbuf, hLbuf);
        k_scanC<<<BB * 32 * NC, 256, 0, stream>>>(delta, uc, BC, Ali, Pbuf, hLbuf, Dpi, xz, y_hi, y_lo);
        k_gemm_out<<<1024, 256, 0, stream>>>(y_hi, y_lo,
                                             ow_hi + (size_t)i * 131072, ow_lo + (size_t)i * 131072,
                                             p01, p23);
        k_ln_res<<<ROWS / 4, 256, 0, stream>>>(p01, p23, gi, bi, h, h_hi, h_lo);
    }

    k_meanp<<<32, 256, 0, stream>>>(h, part);
    k_head<<<BB, 256, 0, stream>>>(part, head_w1, head_b1, head_w2, head_b2, (float*)d_out);
}